// Round 1
// baseline (534.203 us; speedup 1.0000x reference)
//
#include <hip/hip_runtime.h>

typedef unsigned short ushort_t;
typedef short bf16x8 __attribute__((ext_vector_type(8)));
typedef float f32x4 __attribute__((ext_vector_type(4)));

#define B_    2
#define T_    2048
#define C_    2048
#define H_    16
#define DH_   128
#define BT_   4096
#define NQKV  2304

// workspace offsets (bytes), all 256-aligned
#define OFF_XB   0UL            // xb (bf16 x) [4096][2048] = 16777216 B ; reused as y after GEMM1
#define OFF_WT   16777216UL     // WT_all [2304][2048] bf16 (rows: Wq^T cols 0..2047, Wk^T 2048.., Wv^T 2176..)
#define OFF_WOT  26214400UL     // WoT [2048][2048] bf16
#define OFF_QKV  34603008UL     // qkv [4096][2304] bf16
#define OFF_VT   53477376UL     // vT [2][128][2048] bf16
#define OFF_FLAG 54525952UL     // int flag: 1 = inputs are bf16, 0 = fp32

__device__ __forceinline__ ushort_t f2bf(float f) {
  union { float f; unsigned u; } v; v.f = f;
  unsigned r = v.u + 0x7fffu + ((v.u >> 16) & 1u);
  return (ushort_t)(r >> 16);
}
__device__ __forceinline__ float bf2f(ushort_t u) {
  union { float f; unsigned u; } v; v.u = ((unsigned)u) << 16;
  return v.f;
}

__device__ __forceinline__ void gload_lds16(const ushort_t* g, ushort_t* l) {
  __builtin_amdgcn_global_load_lds((__attribute__((address_space(1))) void*)g,
                                   (__attribute__((address_space(3))) void*)l,
                                   16, 0, 0);
}

// ---------------- dtype detector -------------------------------------------
// bf16 arrays: every ushort is a sane bf16 (exponent in a narrow band).
// fp32 arrays read as ushorts: even indices are mantissa bits -> random exponents.
__global__ void detect_dtype(const ushort_t* x, int* flag) {
  if (threadIdx.x == 0 && blockIdx.x == 0) {
    int sane = 0;
    for (int i = 0; i < 32; ++i) {
      ushort_t u = x[2 * i];
      int e = (u >> 7) & 0xFF;
      if (u == 0 || (e >= 100 && e <= 140)) ++sane;
    }
    *flag = (sane >= 24) ? 1 : 0;
  }
}

// ---------------- cast x -> bf16 -------------------------------------------
__global__ __launch_bounds__(256) void cast_x(const void* __restrict__ xin,
                                              ushort_t* __restrict__ xb,
                                              const int* __restrict__ flag, int n8) {
  int i = blockIdx.x * 256 + threadIdx.x;
  if (i >= n8) return;
  if (*flag) {
    *(bf16x8*)(xb + (size_t)i * 8) = *(const bf16x8*)((const ushort_t*)xin + (size_t)i * 8);
  } else {
    const float* xf = (const float*)xin;
    f32x4 a = *(const f32x4*)(xf + (size_t)i * 8);
    f32x4 b = *(const f32x4*)(xf + (size_t)i * 8 + 4);
    bf16x8 o;
    o[0] = (short)f2bf(a[0]); o[1] = (short)f2bf(a[1]);
    o[2] = (short)f2bf(a[2]); o[3] = (short)f2bf(a[3]);
    o[4] = (short)f2bf(b[0]); o[5] = (short)f2bf(b[1]);
    o[6] = (short)f2bf(b[2]); o[7] = (short)f2bf(b[3]);
    *(bf16x8*)(xb + (size_t)i * 8) = o;
  }
}

// ---------------- transpose+cast weight: dst[row_off+c][r] = src[r][c] -----
__global__ __launch_bounds__(256) void transpose_cast(const void* __restrict__ src,
                                                      ushort_t* __restrict__ dst,
                                                      const int* __restrict__ flag,
                                                      int rows, int cols, int dst_ld,
                                                      int dst_row_off) {
  __shared__ float tile[32][33];
  int c0 = blockIdx.x * 32, r0 = blockIdx.y * 32;
  int tx = threadIdx.x & 31, ty = threadIdx.x >> 5;  // 32 x 8
  bool isbf = (*flag != 0);
#pragma unroll
  for (int j = 0; j < 4; ++j) {
    int r = r0 + ty + j * 8;
    float v;
    if (isbf) v = bf2f(((const ushort_t*)src)[(size_t)r * cols + c0 + tx]);
    else      v = ((const float*)src)[(size_t)r * cols + c0 + tx];
    tile[ty + j * 8][tx] = v;
  }
  __syncthreads();
#pragma unroll
  for (int j = 0; j < 4; ++j) {
    int c = c0 + ty + j * 8;
    dst[(size_t)(dst_row_off + c) * dst_ld + r0 + tx] = f2bf(tile[tx][ty + j * 8]);
  }
}

// ---------------- transpose v slice of qkv -> vT (bf16) --------------------
__global__ __launch_bounds__(256) void transpose_v(const ushort_t* __restrict__ qkv,
                                                   ushort_t* __restrict__ vT) {
  __shared__ ushort_t tile[32][33];
  int b = blockIdx.z;
  int t0 = blockIdx.x * 32, d0 = blockIdx.y * 32;
  int tx = threadIdx.x & 31, ty = threadIdx.x >> 5;
#pragma unroll
  for (int j = 0; j < 4; ++j) {
    int t = t0 + ty + j * 8;
    tile[ty + j * 8][tx] = qkv[(size_t)(b * T_ + t) * NQKV + 2176 + d0 + tx];
  }
  __syncthreads();
#pragma unroll
  for (int j = 0; j < 4; ++j) {
    int d = d0 + ty + j * 8;
    vT[(size_t)b * (DH_ * T_) + (size_t)d * T_ + t0 + tx] = tile[tx][ty + j * 8];
  }
}

// ---------------- GEMM: C[m][n] = sum_k A[m][k] * Bt[n][k]  (bf16 MFMA) ----
// 128x128 tile, BK=32, 256 threads = 4 waves (2x2), each wave 64x64.
__global__ __launch_bounds__(256) void gemm_bt(const ushort_t* __restrict__ A,
                                               const ushort_t* __restrict__ Bt,
                                               void* __restrict__ Cv,
                                               int M, int N, int K,
                                               int is_final, const int* __restrict__ flag) {
  __shared__ __align__(16) ushort_t As[128 * 32];
  __shared__ __align__(16) ushort_t Bs[128 * 32];
  const int tid = threadIdx.x;
  const int lane = tid & 63;
  const int wid = tid >> 6;
  const int m0 = blockIdx.y * 128;
  const int n0 = blockIdx.x * 128;
  const int wr = wid >> 1, wc = wid & 1;
  const int l15 = lane & 15, l4 = lane >> 4;

  f32x4 zero = {0.f, 0.f, 0.f, 0.f};
  f32x4 acc[4][4];
#pragma unroll
  for (int r = 0; r < 4; ++r)
#pragma unroll
    for (int c = 0; c < 4; ++c) acc[r][c] = zero;

  const ushort_t* ga = A + (size_t)(m0 + (tid >> 2)) * K + (tid & 3) * 8;
  const ushort_t* gb = Bt + (size_t)(n0 + (tid >> 2)) * K + (tid & 3) * 8;
  ushort_t* lA = As + wid * 512;  // wave-uniform base (bytes: wid*1024)
  ushort_t* lB = Bs + wid * 512;
  const size_t stride64 = (size_t)64 * K;

  for (int k0 = 0; k0 < K; k0 += 32) {
    __syncthreads();
    gload_lds16(ga + k0, lA);
    gload_lds16(ga + k0 + stride64, lA + 2048);
    gload_lds16(gb + k0, lB);
    gload_lds16(gb + k0 + stride64, lB + 2048);
    __syncthreads();

    bf16x8 af[4], bfr[4];
#pragma unroll
    for (int r = 0; r < 4; ++r)
      af[r] = *(const bf16x8*)&As[(wr * 64 + r * 16 + l15) * 32 + l4 * 8];
#pragma unroll
    for (int c = 0; c < 4; ++c)
      bfr[c] = *(const bf16x8*)&Bs[(wc * 64 + c * 16 + l15) * 32 + l4 * 8];
#pragma unroll
    for (int r = 0; r < 4; ++r)
#pragma unroll
      for (int c = 0; c < 4; ++c)
        acc[r][c] = __builtin_amdgcn_mfma_f32_16x16x32_bf16(af[r], bfr[c], acc[r][c], 0, 0, 0);
  }

  const bool f32out = is_final && (*flag == 0);
#pragma unroll
  for (int r = 0; r < 4; ++r) {
#pragma unroll
    for (int c = 0; c < 4; ++c) {
      int row = m0 + wr * 64 + r * 16 + l4 * 4;
      int col = n0 + wc * 64 + c * 16 + l15;
#pragma unroll
      for (int g = 0; g < 4; ++g) {
        if (f32out) ((float*)Cv)[(size_t)(row + g) * N + col] = acc[r][c][g];
        else ((ushort_t*)Cv)[(size_t)(row + g) * N + col] = f2bf(acc[r][c][g]);
      }
    }
  }
}

// ---------------- flash attention ------------------------------------------
// grid (32 qtiles, 16 heads, 2 batches), 256 threads = 4 waves x 16 q-rows.
// KV tiles of 64; K tile [64][128] and V^T tile [128][64] in LDS, XOR-swizzled.
__global__ __launch_bounds__(256) void attn_kernel(const ushort_t* __restrict__ qkv,
                                                   const ushort_t* __restrict__ vT,
                                                   ushort_t* __restrict__ y) {
  __shared__ __align__(16) ushort_t Ks[64 * 128];
  __shared__ __align__(16) ushort_t Vs[128 * 64];
  __shared__ __align__(16) ushort_t Pl[4][16][72];  // per-wave P, padded stride (144B, 16B-aligned)

  const int tid = threadIdx.x;
  const int lane = tid & 63;
  const int wid = tid >> 6;
  const int h = blockIdx.y;
  const int b = blockIdx.z;
  const int tb = b * T_;
  const int q0 = blockIdx.x * 64 + wid * 16;
  const int l15 = lane & 15, l4 = lane >> 4;

  // Q fragments in registers for the whole block
  bf16x8 qf[4];
  {
    const ushort_t* qbase = qkv + (size_t)(tb + q0 + l15) * NQKV + h * DH_ + l4 * 8;
#pragma unroll
    for (int ks = 0; ks < 4; ++ks) qf[ks] = *(const bf16x8*)(qbase + ks * 32);
  }

  f32x4 zero = {0.f, 0.f, 0.f, 0.f};
  f32x4 o[8];
#pragma unroll
  for (int i = 0; i < 8; ++i) o[i] = zero;
  float mrow[4] = {-1e30f, -1e30f, -1e30f, -1e30f};
  float lrow[4] = {0.f, 0.f, 0.f, 0.f};
  const float sc = 0.08838834764831845f;  // 1/sqrt(128)

  for (int st = 0; st < 32; ++st) {
    const int s0 = st * 64;
    __syncthreads();
    // stage K tile [64][128], swizzled: slot ^= (row&7)
#pragma unroll
    for (int it = 0; it < 4; ++it) {
      int id = tid + it * 256;
      int row = id >> 4, slot = id & 15;
      bf16x8 v = *(const bf16x8*)(qkv + (size_t)(tb + s0 + row) * NQKV + 2048 + slot * 8);
      *(bf16x8*)&Ks[row * 128 + ((slot ^ (row & 7)) << 3)] = v;
    }
    // stage V^T tile [128][64], swizzled
#pragma unroll
    for (int it = 0; it < 4; ++it) {
      int id = tid + it * 256;
      int row = id >> 3, slot = id & 7;
      bf16x8 v = *(const bf16x8*)(vT + (size_t)b * (DH_ * T_) + (size_t)row * T_ + s0 + slot * 8);
      *(bf16x8*)&Vs[row * 64 + ((slot ^ (row & 7)) << 3)] = v;
    }
    __syncthreads();

    // S = Q K^T  (per wave: [16 q][64 s])
    f32x4 sa[4];
#pragma unroll
    for (int c = 0; c < 4; ++c) {
      sa[c] = zero;
      int srow = c * 16 + l15;
      int sw = srow & 7;
#pragma unroll
      for (int ks = 0; ks < 4; ++ks) {
        bf16x8 kf = *(const bf16x8*)&Ks[srow * 128 + (((ks * 4 + l4) ^ sw) << 3)];
        sa[c] = __builtin_amdgcn_mfma_f32_16x16x32_bf16(qf[ks], kf, sa[c], 0, 0, 0);
      }
    }

    // online softmax (rows live in 16-lane groups; reduce via shfl_xor 1/2/4/8)
    float alpha[4];
#pragma unroll
    for (int r = 0; r < 4; ++r) {
#pragma unroll
      for (int c = 0; c < 4; ++c) sa[c][r] *= sc;
      float m = fmaxf(fmaxf(sa[0][r], sa[1][r]), fmaxf(sa[2][r], sa[3][r]));
      m = fmaxf(m, __shfl_xor(m, 1));
      m = fmaxf(m, __shfl_xor(m, 2));
      m = fmaxf(m, __shfl_xor(m, 4));
      m = fmaxf(m, __shfl_xor(m, 8));
      float mn = fmaxf(mrow[r], m);
      alpha[r] = __expf(mrow[r] - mn);
      mrow[r] = mn;
      float s = 0.f;
#pragma unroll
      for (int c = 0; c < 4; ++c) {
        float p = __expf(sa[c][r] - mn);
        sa[c][r] = p;
        s += p;
      }
      s += __shfl_xor(s, 1);
      s += __shfl_xor(s, 2);
      s += __shfl_xor(s, 4);
      s += __shfl_xor(s, 8);
      lrow[r] = lrow[r] * alpha[r] + s;
    }

    // P -> LDS (C-frag layout -> A-frag layout re-distribution)
#pragma unroll
    for (int c = 0; c < 4; ++c)
#pragma unroll
      for (int r = 0; r < 4; ++r)
        Pl[wid][l4 * 4 + r][c * 16 + l15] = f2bf(sa[c][r]);

    // rescale O
#pragma unroll
    for (int nb = 0; nb < 8; ++nb)
#pragma unroll
      for (int r = 0; r < 4; ++r) o[nb][r] *= alpha[r];

    // PV: o[16 q][128 d] += P[16 q][64 s] * V[64 s][128 d]
    bf16x8 pa0 = *(const bf16x8*)&Pl[wid][l15][l4 * 8];
    bf16x8 pa1 = *(const bf16x8*)&Pl[wid][l15][32 + l4 * 8];
#pragma unroll
    for (int nb = 0; nb < 8; ++nb) {
      int vrow = nb * 16 + l15;
      int sw = vrow & 7;
      bf16x8 vb0 = *(const bf16x8*)&Vs[vrow * 64 + ((l4 ^ sw) << 3)];
      o[nb] = __builtin_amdgcn_mfma_f32_16x16x32_bf16(pa0, vb0, o[nb], 0, 0, 0);
      bf16x8 vb1 = *(const bf16x8*)&Vs[vrow * 64 + (((4 + l4) ^ sw) << 3)];
      o[nb] = __builtin_amdgcn_mfma_f32_16x16x32_bf16(pa1, vb1, o[nb], 0, 0, 0);
    }
  }

  // epilogue: y[token][h*128 + d] = o / l
#pragma unroll
  for (int nb = 0; nb < 8; ++nb) {
#pragma unroll
    for (int r = 0; r < 4; ++r) {
      int qrow = tb + q0 + l4 * 4 + r;
      y[(size_t)qrow * C_ + h * DH_ + nb * 16 + l15] = f2bf(o[nb][r] / lrow[r]);
    }
  }
}

// ---------------- launch ----------------------------------------------------
extern "C" void kernel_launch(void* const* d_in, const int* in_sizes, int n_in,
                              void* d_out, int out_size, void* d_ws, size_t ws_size,
                              hipStream_t stream) {
  (void)in_sizes; (void)n_in; (void)out_size; (void)ws_size;
  const void* x  = d_in[0];
  const void* Wq = d_in[1];
  const void* Wk = d_in[2];
  const void* Wv = d_in[3];
  const void* Wo = d_in[4];

  char* ws = (char*)d_ws;
  ushort_t* xb  = (ushort_t*)(ws + OFF_XB);   // also reused as y
  ushort_t* WT  = (ushort_t*)(ws + OFF_WT);
  ushort_t* WoT = (ushort_t*)(ws + OFF_WOT);
  ushort_t* qkv = (ushort_t*)(ws + OFF_QKV);
  ushort_t* vTp = (ushort_t*)(ws + OFF_VT);
  int* flag     = (int*)(ws + OFF_FLAG);

  detect_dtype<<<1, 1, 0, stream>>>((const ushort_t*)x, flag);

  // x -> bf16
  cast_x<<<4096, 256, 0, stream>>>(x, xb, flag, (BT_ * C_) / 8);

  // weights -> transposed bf16
  transpose_cast<<<dim3(64, 64), 256, 0, stream>>>(Wq, WT, flag, 2048, 2048, 2048, 0);
  transpose_cast<<<dim3(4, 64), 256, 0, stream>>>(Wk, WT, flag, 2048, 128, 2048, 2048);
  transpose_cast<<<dim3(4, 64), 256, 0, stream>>>(Wv, WT, flag, 2048, 128, 2048, 2176);
  transpose_cast<<<dim3(64, 64), 256, 0, stream>>>(Wo, WoT, flag, 2048, 2048, 2048, 0);

  // qkv = xb @ WT^T   [4096][2304]
  gemm_bt<<<dim3(NQKV / 128, BT_ / 128), 256, 0, stream>>>(xb, WT, qkv, BT_, NQKV, C_, 0, flag);

  // v -> vT
  transpose_v<<<dim3(T_ / 32, DH_ / 32, B_), 256, 0, stream>>>(qkv, vTp);

  // attention -> y (reuses xb buffer)
  attn_kernel<<<dim3(T_ / 64, H_, B_), 256, 0, stream>>>(qkv, vTp, xb);

  // out = y @ WoT^T
  gemm_bt<<<dim3(C_ / 128, BT_ / 128), 256, 0, stream>>>(xb, WoT, d_out, BT_, C_, C_, 1, flag);
}

// Round 2
// 395.857 us; speedup vs baseline: 1.3495x; 1.3495x over previous
//
#include <hip/hip_runtime.h>

typedef unsigned short ushort_t;
typedef short bf16x8 __attribute__((ext_vector_type(8)));
typedef float f32x4 __attribute__((ext_vector_type(4)));

#define B_    2
#define T_    2048
#define C_    2048
#define H_    16
#define DH_   128
#define BT_   4096
#define NQKV  2304

// workspace offsets (bytes), all 256-aligned
#define OFF_XB   0UL            // xb (bf16 x) [4096][2048] = 16777216 B ; reused as y after GEMM1
#define OFF_WT   16777216UL     // WT_all [2304][2048] bf16 (rows: Wq^T cols 0..2047, Wk^T 2048.., Wv^T 2176..)
#define OFF_WOT  26214400UL     // WoT [2048][2048] bf16
#define OFF_QKV  34603008UL     // qkv [4096][2304] bf16
#define OFF_VT   53477376UL     // vT [2][128][2048] bf16
#define OFF_FLAG 54525952UL     // int flag: 1 = inputs are bf16, 0 = fp32

__device__ __forceinline__ ushort_t f2bf(float f) {
  union { float f; unsigned u; } v; v.f = f;
  unsigned r = v.u + 0x7fffu + ((v.u >> 16) & 1u);
  return (ushort_t)(r >> 16);
}
__device__ __forceinline__ float bf2f(ushort_t u) {
  union { float f; unsigned u; } v; v.u = ((unsigned)u) << 16;
  return v.f;
}

__device__ __forceinline__ void gload_lds16(const ushort_t* g, ushort_t* l) {
  __builtin_amdgcn_global_load_lds((__attribute__((address_space(1))) void*)g,
                                   (__attribute__((address_space(3))) void*)l,
                                   16, 0, 0);
}

// ---------------- dtype detector -------------------------------------------
__global__ void detect_dtype(const ushort_t* x, int* flag) {
  if (threadIdx.x == 0 && blockIdx.x == 0) {
    int sane = 0;
    for (int i = 0; i < 32; ++i) {
      ushort_t u = x[2 * i];
      int e = (u >> 7) & 0xFF;
      if (u == 0 || (e >= 100 && e <= 140)) ++sane;
    }
    *flag = (sane >= 24) ? 1 : 0;
  }
}

// ---------------- cast x -> bf16 -------------------------------------------
__global__ __launch_bounds__(256) void cast_x(const void* __restrict__ xin,
                                              ushort_t* __restrict__ xb,
                                              const int* __restrict__ flag, int n8) {
  int i = blockIdx.x * 256 + threadIdx.x;
  if (i >= n8) return;
  if (*flag) {
    *(bf16x8*)(xb + (size_t)i * 8) = *(const bf16x8*)((const ushort_t*)xin + (size_t)i * 8);
  } else {
    const float* xf = (const float*)xin;
    f32x4 a = *(const f32x4*)(xf + (size_t)i * 8);
    f32x4 b = *(const f32x4*)(xf + (size_t)i * 8 + 4);
    bf16x8 o;
    o[0] = (short)f2bf(a[0]); o[1] = (short)f2bf(a[1]);
    o[2] = (short)f2bf(a[2]); o[3] = (short)f2bf(a[3]);
    o[4] = (short)f2bf(b[0]); o[5] = (short)f2bf(b[1]);
    o[6] = (short)f2bf(b[2]); o[7] = (short)f2bf(b[3]);
    *(bf16x8*)(xb + (size_t)i * 8) = o;
  }
}

// ---------------- transpose+cast weight: dst[row_off+c][r] = src[r][c] -----
__global__ __launch_bounds__(256) void transpose_cast(const void* __restrict__ src,
                                                      ushort_t* __restrict__ dst,
                                                      const int* __restrict__ flag,
                                                      int rows, int cols, int dst_ld,
                                                      int dst_row_off) {
  __shared__ float tile[32][33];
  int c0 = blockIdx.x * 32, r0 = blockIdx.y * 32;
  int tx = threadIdx.x & 31, ty = threadIdx.x >> 5;  // 32 x 8
  bool isbf = (*flag != 0);
#pragma unroll
  for (int j = 0; j < 4; ++j) {
    int r = r0 + ty + j * 8;
    float v;
    if (isbf) v = bf2f(((const ushort_t*)src)[(size_t)r * cols + c0 + tx]);
    else      v = ((const float*)src)[(size_t)r * cols + c0 + tx];
    tile[ty + j * 8][tx] = v;
  }
  __syncthreads();
#pragma unroll
  for (int j = 0; j < 4; ++j) {
    int c = c0 + ty + j * 8;
    dst[(size_t)(dst_row_off + c) * dst_ld + r0 + tx] = f2bf(tile[tx][ty + j * 8]);
  }
}

// ---------------- transpose v slice of qkv -> vT (bf16) --------------------
__global__ __launch_bounds__(256) void transpose_v(const ushort_t* __restrict__ qkv,
                                                   ushort_t* __restrict__ vT) {
  __shared__ ushort_t tile[32][33];
  int b = blockIdx.z;
  int t0 = blockIdx.x * 32, d0 = blockIdx.y * 32;
  int tx = threadIdx.x & 31, ty = threadIdx.x >> 5;
#pragma unroll
  for (int j = 0; j < 4; ++j) {
    int t = t0 + ty + j * 8;
    tile[ty + j * 8][tx] = qkv[(size_t)(b * T_ + t) * NQKV + 2176 + d0 + tx];
  }
  __syncthreads();
#pragma unroll
  for (int j = 0; j < 4; ++j) {
    int d = d0 + ty + j * 8;
    vT[(size_t)b * (DH_ * T_) + (size_t)d * T_ + t0 + tx] = tile[tx][ty + j * 8];
  }
}

// ---------------- GEMM: C[m][n] = sum_k A[m][k] * Bt[n][k]  (bf16 MFMA) ----
// 128x128 tile, BK=32, 256 threads = 4 waves (2x2), each wave 64x64.
__global__ __launch_bounds__(256) void gemm_bt(const ushort_t* __restrict__ A,
                                               const ushort_t* __restrict__ Bt,
                                               void* __restrict__ Cv,
                                               int M, int N, int K,
                                               int is_final, const int* __restrict__ flag) {
  __shared__ __align__(16) ushort_t As[128 * 32];
  __shared__ __align__(16) ushort_t Bs[128 * 32];
  const int tid = threadIdx.x;
  const int lane = tid & 63;
  const int wid = tid >> 6;
  const int m0 = blockIdx.y * 128;
  const int n0 = blockIdx.x * 128;
  const int wr = wid >> 1, wc = wid & 1;
  const int l15 = lane & 15, l4 = lane >> 4;

  f32x4 zero = {0.f, 0.f, 0.f, 0.f};
  f32x4 acc[4][4];
#pragma unroll
  for (int r = 0; r < 4; ++r)
#pragma unroll
    for (int c = 0; c < 4; ++c) acc[r][c] = zero;

  const ushort_t* ga = A + (size_t)(m0 + (tid >> 2)) * K + (tid & 3) * 8;
  const ushort_t* gb = Bt + (size_t)(n0 + (tid >> 2)) * K + (tid & 3) * 8;
  ushort_t* lA = As + wid * 512;  // wave-uniform base (bytes: wid*1024)
  ushort_t* lB = Bs + wid * 512;
  const size_t stride64 = (size_t)64 * K;

  for (int k0 = 0; k0 < K; k0 += 32) {
    __syncthreads();
    gload_lds16(ga + k0, lA);
    gload_lds16(ga + k0 + stride64, lA + 2048);
    gload_lds16(gb + k0, lB);
    gload_lds16(gb + k0 + stride64, lB + 2048);
    __syncthreads();

    bf16x8 af[4], bfr[4];
#pragma unroll
    for (int r = 0; r < 4; ++r)
      af[r] = *(const bf16x8*)&As[(wr * 64 + r * 16 + l15) * 32 + l4 * 8];
#pragma unroll
    for (int c = 0; c < 4; ++c)
      bfr[c] = *(const bf16x8*)&Bs[(wc * 64 + c * 16 + l15) * 32 + l4 * 8];
#pragma unroll
    for (int r = 0; r < 4; ++r)
#pragma unroll
      for (int c = 0; c < 4; ++c)
        acc[r][c] = __builtin_amdgcn_mfma_f32_16x16x32_bf16(af[r], bfr[c], acc[r][c], 0, 0, 0);
  }

  const bool f32out = is_final && (*flag == 0);
#pragma unroll
  for (int r = 0; r < 4; ++r) {
#pragma unroll
    for (int c = 0; c < 4; ++c) {
      int row = m0 + wr * 64 + r * 16 + l4 * 4;
      int col = n0 + wc * 64 + c * 16 + l15;
#pragma unroll
      for (int g = 0; g < 4; ++g) {
        if (f32out) ((float*)Cv)[(size_t)(row + g) * N + col] = acc[r][c][g];
        else ((ushort_t*)Cv)[(size_t)(row + g) * N + col] = f2bf(acc[r][c][g]);
      }
    }
  }
}

// ---------------- flash attention (v2: MQA head-sharing + gload_lds) -------
// grid (32 qtiles, 8 head-pairs, 2 batches), 512 threads = 8 waves.
// Waves 0-3 -> head 2*by, waves 4-7 -> head 2*by+1; each wave: 16 q-rows.
// K tile [64][128] and V^T tile [128][64] staged ONCE per step via
// global_load_lds with pre-swizzled global source (LDS dest linear).
__global__ __launch_bounds__(512, 4) void attn_kernel(const ushort_t* __restrict__ qkv,
                                                      const ushort_t* __restrict__ vT,
                                                      ushort_t* __restrict__ y) {
  __shared__ __align__(16) ushort_t Ks[64 * 128];
  __shared__ __align__(16) ushort_t Vs[128 * 64];
  __shared__ __align__(16) ushort_t Pl[8][16][72];  // per-wave P, padded stride

  const int tid = threadIdx.x;
  const int lane = tid & 63;
  const int wid = tid >> 6;                 // 0..7
  const int h = blockIdx.y * 2 + (wid >> 2);
  const int b = blockIdx.z;
  const int tb = b * T_;
  const int q0 = blockIdx.x * 64 + (wid & 3) * 16;
  const int l15 = lane & 15, l4 = lane >> 4;

  // Q fragments in registers for the whole block
  bf16x8 qf[4];
  {
    const ushort_t* qbase = qkv + (size_t)(tb + q0 + l15) * NQKV + h * DH_ + l4 * 8;
#pragma unroll
    for (int ks = 0; ks < 4; ++ks) qf[ks] = *(const bf16x8*)(qbase + ks * 32);
  }

  // precomputed staging addresses (pre-swizzled global source, linear LDS dest)
  const ushort_t* ksrc[2];
  const ushort_t* vsrc[2];
  ushort_t* kdst[2];
  ushort_t* vdst[2];
#pragma unroll
  for (int it = 0; it < 2; ++it) {
    int id = tid + it * 512;
    int krow = id >> 4, kslot = id & 15;
    ksrc[it] = qkv + (size_t)(tb + krow) * NQKV + 2048 + ((kslot ^ (krow & 7)) << 3);
    kdst[it] = Ks + (size_t)(it * 512 + (wid << 6)) * 8;  // wave-uniform base
    int vrow = id >> 3, vslot = id & 7;
    vsrc[it] = vT + (size_t)b * (DH_ * T_) + (size_t)vrow * T_ + ((vslot ^ (vrow & 7)) << 3);
    vdst[it] = Vs + (size_t)(it * 512 + (wid << 6)) * 8;
  }

  f32x4 zero = {0.f, 0.f, 0.f, 0.f};
  f32x4 o[8];
#pragma unroll
  for (int i = 0; i < 8; ++i) o[i] = zero;
  float mrow[4] = {-1e30f, -1e30f, -1e30f, -1e30f};
  float lrow[4] = {0.f, 0.f, 0.f, 0.f};
  const float sc = 0.08838834764831845f;  // 1/sqrt(128)

  for (int st = 0; st < 32; ++st) {
    const int s0 = st * 64;
    __syncthreads();  // previous tile fully consumed
    gload_lds16(ksrc[0] + (size_t)s0 * NQKV, kdst[0]);
    gload_lds16(ksrc[1] + (size_t)s0 * NQKV, kdst[1]);
    gload_lds16(vsrc[0] + s0, vdst[0]);
    gload_lds16(vsrc[1] + s0, vdst[1]);
    __syncthreads();  // compiler drains vmcnt before barrier -> tile ready

    // S = Q K^T  (per wave: [16 q][64 s])
    f32x4 sa[4];
#pragma unroll
    for (int c = 0; c < 4; ++c) {
      sa[c] = zero;
      int srow = c * 16 + l15;
      int sw = srow & 7;
#pragma unroll
      for (int ks = 0; ks < 4; ++ks) {
        bf16x8 kf = *(const bf16x8*)&Ks[srow * 128 + (((ks * 4 + l4) ^ sw) << 3)];
        sa[c] = __builtin_amdgcn_mfma_f32_16x16x32_bf16(qf[ks], kf, sa[c], 0, 0, 0);
      }
    }

    // online softmax (rows live in 16-lane groups; reduce via shfl_xor 1/2/4/8)
    float alpha[4];
#pragma unroll
    for (int r = 0; r < 4; ++r) {
#pragma unroll
      for (int c = 0; c < 4; ++c) sa[c][r] *= sc;
      float m = fmaxf(fmaxf(sa[0][r], sa[1][r]), fmaxf(sa[2][r], sa[3][r]));
      m = fmaxf(m, __shfl_xor(m, 1));
      m = fmaxf(m, __shfl_xor(m, 2));
      m = fmaxf(m, __shfl_xor(m, 4));
      m = fmaxf(m, __shfl_xor(m, 8));
      float mn = fmaxf(mrow[r], m);
      alpha[r] = __expf(mrow[r] - mn);
      mrow[r] = mn;
      float s = 0.f;
#pragma unroll
      for (int c = 0; c < 4; ++c) {
        float p = __expf(sa[c][r] - mn);
        sa[c][r] = p;
        s += p;
      }
      s += __shfl_xor(s, 1);
      s += __shfl_xor(s, 2);
      s += __shfl_xor(s, 4);
      s += __shfl_xor(s, 8);
      lrow[r] = lrow[r] * alpha[r] + s;
    }

    // P -> LDS (C-frag layout -> A-frag layout re-distribution)
#pragma unroll
    for (int c = 0; c < 4; ++c)
#pragma unroll
      for (int r = 0; r < 4; ++r)
        Pl[wid][l4 * 4 + r][c * 16 + l15] = f2bf(sa[c][r]);

    // rescale O
#pragma unroll
    for (int nb = 0; nb < 8; ++nb)
#pragma unroll
      for (int r = 0; r < 4; ++r) o[nb][r] *= alpha[r];

    // PV: o[16 q][128 d] += P[16 q][64 s] * V[64 s][128 d]
    bf16x8 pa0 = *(const bf16x8*)&Pl[wid][l15][l4 * 8];
    bf16x8 pa1 = *(const bf16x8*)&Pl[wid][l15][32 + l4 * 8];
#pragma unroll
    for (int nb = 0; nb < 8; ++nb) {
      int vrow = nb * 16 + l15;
      int sw = vrow & 7;
      bf16x8 vb0 = *(const bf16x8*)&Vs[vrow * 64 + ((l4 ^ sw) << 3)];
      o[nb] = __builtin_amdgcn_mfma_f32_16x16x32_bf16(pa0, vb0, o[nb], 0, 0, 0);
      bf16x8 vb1 = *(const bf16x8*)&Vs[vrow * 64 + (((4 + l4) ^ sw) << 3)];
      o[nb] = __builtin_amdgcn_mfma_f32_16x16x32_bf16(pa1, vb1, o[nb], 0, 0, 0);
    }
  }

  // epilogue: y[token][h*128 + d] = o / l
#pragma unroll
  for (int nb = 0; nb < 8; ++nb) {
#pragma unroll
    for (int r = 0; r < 4; ++r) {
      int qrow = tb + q0 + l4 * 4 + r;
      y[(size_t)qrow * C_ + h * DH_ + nb * 16 + l15] = f2bf(o[nb][r] / lrow[r]);
    }
  }
}

// ---------------- launch ----------------------------------------------------
extern "C" void kernel_launch(void* const* d_in, const int* in_sizes, int n_in,
                              void* d_out, int out_size, void* d_ws, size_t ws_size,
                              hipStream_t stream) {
  (void)in_sizes; (void)n_in; (void)out_size; (void)ws_size;
  const void* x  = d_in[0];
  const void* Wq = d_in[1];
  const void* Wk = d_in[2];
  const void* Wv = d_in[3];
  const void* Wo = d_in[4];

  char* ws = (char*)d_ws;
  ushort_t* xb  = (ushort_t*)(ws + OFF_XB);   // also reused as y
  ushort_t* WT  = (ushort_t*)(ws + OFF_WT);
  ushort_t* WoT = (ushort_t*)(ws + OFF_WOT);
  ushort_t* qkv = (ushort_t*)(ws + OFF_QKV);
  ushort_t* vTp = (ushort_t*)(ws + OFF_VT);
  int* flag     = (int*)(ws + OFF_FLAG);

  detect_dtype<<<1, 1, 0, stream>>>((const ushort_t*)x, flag);

  // x -> bf16
  cast_x<<<4096, 256, 0, stream>>>(x, xb, flag, (BT_ * C_) / 8);

  // weights -> transposed bf16
  transpose_cast<<<dim3(64, 64), 256, 0, stream>>>(Wq, WT, flag, 2048, 2048, 2048, 0);
  transpose_cast<<<dim3(4, 64), 256, 0, stream>>>(Wk, WT, flag, 2048, 128, 2048, 2048);
  transpose_cast<<<dim3(4, 64), 256, 0, stream>>>(Wv, WT, flag, 2048, 128, 2048, 2176);
  transpose_cast<<<dim3(64, 64), 256, 0, stream>>>(Wo, WoT, flag, 2048, 2048, 2048, 0);

  // qkv = xb @ WT^T   [4096][2304]
  gemm_bt<<<dim3(NQKV / 128, BT_ / 128), 256, 0, stream>>>(xb, WT, qkv, BT_, NQKV, C_, 0, flag);

  // v -> vT
  transpose_v<<<dim3(T_ / 32, DH_ / 32, B_), 256, 0, stream>>>(qkv, vTp);

  // attention -> y (reuses xb buffer), MQA: K/V shared across 2 heads/block
  attn_kernel<<<dim3(T_ / 64, H_ / 2, B_), 512, 0, stream>>>(qkv, vTp, xb);

  // out = y @ WoT^T
  gemm_bt<<<dim3(C_ / 128, BT_ / 128), 256, 0, stream>>>(xb, WoT, d_out, BT_, C_, C_, 1, flag);
}

// Round 3
// 363.209 us; speedup vs baseline: 1.4708x; 1.0899x over previous
//
#include <hip/hip_runtime.h>

typedef unsigned short ushort_t;
typedef short bf16x8 __attribute__((ext_vector_type(8)));
typedef float f32x4 __attribute__((ext_vector_type(4)));

#define B_    2
#define T_    2048
#define C_    2048
#define H_    16
#define DH_   128
#define BT_   4096
#define NQKV  2304

// workspace offsets (bytes), all 256-aligned
#define OFF_XB   0UL            // xb (bf16 x) [4096][2048] ; reused as y after attention
#define OFF_WT   16777216UL     // WT_all [2304][2048] bf16
#define OFF_WOT  26214400UL     // WoT [2048][2048] bf16
#define OFF_QKV  34603008UL     // qkv [4096][2304] bf16 (q region pre-scaled by 1/sqrt(128)*log2e)
#define OFF_VT   53477376UL     // vT [2][128][2048] bf16
#define OFF_FLAG 54525952UL     // int flag: 1 = inputs are bf16, 0 = fp32

__device__ __forceinline__ ushort_t f2bf(float f) {
  union { float f; unsigned u; } v; v.f = f;
  unsigned r = v.u + 0x7fffu + ((v.u >> 16) & 1u);
  return (ushort_t)(r >> 16);
}
__device__ __forceinline__ float bf2f(ushort_t u) {
  union { float f; unsigned u; } v; v.u = ((unsigned)u) << 16;
  return v.f;
}
__device__ __forceinline__ int cvtpk_bf16(float lo, float hi) {
  int r;
  asm("v_cvt_pk_bf16_f32 %0, %1, %2" : "=v"(r) : "v"(lo), "v"(hi));
  return r;
}
__device__ __forceinline__ bf16x8 mkfrag(int d0, int d1, int d2, int d3) {
  union { int i[4]; bf16x8 v; } u;
  u.i[0] = d0; u.i[1] = d1; u.i[2] = d2; u.i[3] = d3;
  return u.v;
}

__device__ __forceinline__ void gload_lds16(const ushort_t* g, ushort_t* l) {
  __builtin_amdgcn_global_load_lds((__attribute__((address_space(1))) void*)g,
                                   (__attribute__((address_space(3))) void*)l,
                                   16, 0, 0);
}

// ---------------- dtype detector -------------------------------------------
__global__ void detect_dtype(const ushort_t* x, int* flag) {
  if (threadIdx.x == 0 && blockIdx.x == 0) {
    int sane = 0;
    for (int i = 0; i < 32; ++i) {
      ushort_t u = x[2 * i];
      int e = (u >> 7) & 0xFF;
      if (u == 0 || (e >= 100 && e <= 140)) ++sane;
    }
    *flag = (sane >= 24) ? 1 : 0;
  }
}

// ---------------- cast x -> bf16 -------------------------------------------
__global__ __launch_bounds__(256) void cast_x(const void* __restrict__ xin,
                                              ushort_t* __restrict__ xb,
                                              const int* __restrict__ flag, int n8) {
  int i = blockIdx.x * 256 + threadIdx.x;
  if (i >= n8) return;
  if (*flag) {
    *(bf16x8*)(xb + (size_t)i * 8) = *(const bf16x8*)((const ushort_t*)xin + (size_t)i * 8);
  } else {
    const float* xf = (const float*)xin;
    f32x4 a = *(const f32x4*)(xf + (size_t)i * 8);
    f32x4 b = *(const f32x4*)(xf + (size_t)i * 8 + 4);
    bf16x8 o;
    o[0] = (short)f2bf(a[0]); o[1] = (short)f2bf(a[1]);
    o[2] = (short)f2bf(a[2]); o[3] = (short)f2bf(a[3]);
    o[4] = (short)f2bf(b[0]); o[5] = (short)f2bf(b[1]);
    o[6] = (short)f2bf(b[2]); o[7] = (short)f2bf(b[3]);
    *(bf16x8*)(xb + (size_t)i * 8) = o;
  }
}

// ---------------- transpose+cast weight: dst[row_off+c][r] = src[r][c] -----
__global__ __launch_bounds__(256) void transpose_cast(const void* __restrict__ src,
                                                      ushort_t* __restrict__ dst,
                                                      const int* __restrict__ flag,
                                                      int rows, int cols, int dst_ld,
                                                      int dst_row_off) {
  __shared__ float tile[32][33];
  int c0 = blockIdx.x * 32, r0 = blockIdx.y * 32;
  int tx = threadIdx.x & 31, ty = threadIdx.x >> 5;  // 32 x 8
  bool isbf = (*flag != 0);
#pragma unroll
  for (int j = 0; j < 4; ++j) {
    int r = r0 + ty + j * 8;
    float v;
    if (isbf) v = bf2f(((const ushort_t*)src)[(size_t)r * cols + c0 + tx]);
    else      v = ((const float*)src)[(size_t)r * cols + c0 + tx];
    tile[ty + j * 8][tx] = v;
  }
  __syncthreads();
#pragma unroll
  for (int j = 0; j < 4; ++j) {
    int c = c0 + ty + j * 8;
    dst[(size_t)(dst_row_off + c) * dst_ld + r0 + tx] = f2bf(tile[tx][ty + j * 8]);
  }
}

// ---------------- transpose v slice of qkv -> vT (bf16) --------------------
__global__ __launch_bounds__(256) void transpose_v(const ushort_t* __restrict__ qkv,
                                                   ushort_t* __restrict__ vT) {
  __shared__ ushort_t tile[32][33];
  int b = blockIdx.z;
  int t0 = blockIdx.x * 32, d0 = blockIdx.y * 32;
  int tx = threadIdx.x & 31, ty = threadIdx.x >> 5;
#pragma unroll
  for (int j = 0; j < 4; ++j) {
    int t = t0 + ty + j * 8;
    tile[ty + j * 8][tx] = qkv[(size_t)(b * T_ + t) * NQKV + 2176 + d0 + tx];
  }
  __syncthreads();
#pragma unroll
  for (int j = 0; j < 4; ++j) {
    int d = d0 + ty + j * 8;
    vT[(size_t)b * (DH_ * T_) + (size_t)d * T_ + t0 + tx] = tile[tx][ty + j * 8];
  }
}

// ---------------- GEMM: C[m][n] = sum_k A[m][k] * Bt[n][k]  (bf16 MFMA) ----
// 128x128 tile, BK=32, 256 threads = 4 waves (2x2), each wave 64x64.
// Columns < qcols of C are scaled by qscale (used to pre-scale Q by 1/sqrt(d)*log2e).
__global__ __launch_bounds__(256) void gemm_bt(const ushort_t* __restrict__ A,
                                               const ushort_t* __restrict__ Bt,
                                               void* __restrict__ Cv,
                                               int M, int N, int K,
                                               int is_final, const int* __restrict__ flag,
                                               float qscale, int qcols) {
  __shared__ __align__(16) ushort_t As[128 * 32];
  __shared__ __align__(16) ushort_t Bs[128 * 32];
  const int tid = threadIdx.x;
  const int lane = tid & 63;
  const int wid = tid >> 6;
  const int m0 = blockIdx.y * 128;
  const int n0 = blockIdx.x * 128;
  const int wr = wid >> 1, wc = wid & 1;
  const int l15 = lane & 15, l4 = lane >> 4;

  f32x4 zero = {0.f, 0.f, 0.f, 0.f};
  f32x4 acc[4][4];
#pragma unroll
  for (int r = 0; r < 4; ++r)
#pragma unroll
    for (int c = 0; c < 4; ++c) acc[r][c] = zero;

  const ushort_t* ga = A + (size_t)(m0 + (tid >> 2)) * K + (tid & 3) * 8;
  const ushort_t* gb = Bt + (size_t)(n0 + (tid >> 2)) * K + (tid & 3) * 8;
  ushort_t* lA = As + wid * 512;  // wave-uniform base
  ushort_t* lB = Bs + wid * 512;
  const size_t stride64 = (size_t)64 * K;

  for (int k0 = 0; k0 < K; k0 += 32) {
    __syncthreads();
    gload_lds16(ga + k0, lA);
    gload_lds16(ga + k0 + stride64, lA + 2048);
    gload_lds16(gb + k0, lB);
    gload_lds16(gb + k0 + stride64, lB + 2048);
    __syncthreads();

    bf16x8 af[4], bfr[4];
#pragma unroll
    for (int r = 0; r < 4; ++r)
      af[r] = *(const bf16x8*)&As[(wr * 64 + r * 16 + l15) * 32 + l4 * 8];
#pragma unroll
    for (int c = 0; c < 4; ++c)
      bfr[c] = *(const bf16x8*)&Bs[(wc * 64 + c * 16 + l15) * 32 + l4 * 8];
#pragma unroll
    for (int r = 0; r < 4; ++r)
#pragma unroll
      for (int c = 0; c < 4; ++c)
        acc[r][c] = __builtin_amdgcn_mfma_f32_16x16x32_bf16(af[r], bfr[c], acc[r][c], 0, 0, 0);
  }

  const bool f32out = is_final && (*flag == 0);
#pragma unroll
  for (int r = 0; r < 4; ++r) {
#pragma unroll
    for (int c = 0; c < 4; ++c) {
      int row = m0 + wr * 64 + r * 16 + l4 * 4;
      int col = n0 + wc * 64 + c * 16 + l15;
      float s = (col < qcols) ? qscale : 1.0f;
#pragma unroll
      for (int g = 0; g < 4; ++g) {
        float v = acc[r][c][g] * s;
        if (f32out) ((float*)Cv)[(size_t)(row + g) * N + col] = v;
        else ((ushort_t*)Cv)[(size_t)(row + g) * N + col] = f2bf(v);
      }
    }
  }
}

// ---------------- flash attention (v3) --------------------------------------
// grid (32 qtiles, 8 head-pairs, 2 batches), 512 threads = 8 waves.
// Waves 0-3 -> head 2*by, waves 4-7 -> head 2*by+1; each wave: 16 q-rows.
// Double-buffered K [64][128] / V^T [128][64] tiles (XOR-swizzled), staged via
// global_load_lds with pre-swizzled global source; ONE barrier per KV step.
// Swapped QK^T (mfma(K,Q)) -> lane-local softmax (q = lane&15); P re-layout to
// A-frags via cvt_pk_bf16 + shfl (no P LDS). Defer-max (THR=8, exp2 domain).
// Q is pre-scaled by 1/sqrt(128)*log2e in the GEMM1 epilogue.
__global__ __launch_bounds__(512, 4) void attn_kernel(const ushort_t* __restrict__ qkv,
                                                      const ushort_t* __restrict__ vT,
                                                      ushort_t* __restrict__ y) {
  __shared__ __align__(16) ushort_t Ks[2][64 * 128];
  __shared__ __align__(16) ushort_t Vs[2][128 * 64];

  const int tid = threadIdx.x;
  const int lane = tid & 63;
  const int wid = tid >> 6;                 // 0..7
  const int h = blockIdx.y * 2 + (wid >> 2);
  const int b = blockIdx.z;
  const int tb = b * T_;
  const int q0 = blockIdx.x * 64 + (wid & 3) * 16;
  const int l15 = lane & 15, l4 = lane >> 4;

  // Q fragments in registers (pre-scaled by 1/sqrt(d)*log2e at GEMM1 epilogue)
  bf16x8 qf[4];
  {
    const ushort_t* qbase = qkv + (size_t)(tb + q0 + l15) * NQKV + h * DH_ + l4 * 8;
#pragma unroll
    for (int ks = 0; ks < 4; ++ks) qf[ks] = *(const bf16x8*)(qbase + ks * 32);
  }

  // staging addresses (pre-swizzled global source, linear LDS dest)
  const ushort_t* ksrcb[2];
  const ushort_t* vsrcb[2];
  int koff[2], voff[2];
#pragma unroll
  for (int it = 0; it < 2; ++it) {
    int id = tid + it * 512;
    int krow = id >> 4, kslot = id & 15;
    ksrcb[it] = qkv + (size_t)(tb + krow) * NQKV + 2048 + ((kslot ^ (krow & 7)) << 3);
    int vrow = id >> 3, vslot = id & 7;
    vsrcb[it] = vT + (size_t)b * (DH_ * T_) + (size_t)vrow * T_ + ((vslot ^ (vrow & 7)) << 3);
    koff[it] = (it * 512 + (wid << 6)) * 8;  // wave-uniform within buffer
    voff[it] = (it * 512 + (wid << 6)) * 8;
  }

  f32x4 zero = {0.f, 0.f, 0.f, 0.f};
  f32x4 o[8];
#pragma unroll
  for (int i = 0; i < 8; ++i) o[i] = zero;
  float m_s = -1e30f;   // running max (log2 domain) for q = l15
  float l_s = 0.f;      // running denom for q = l15

  // prologue: stage tile 0 into buffer 0
#pragma unroll
  for (int it = 0; it < 2; ++it) {
    gload_lds16(ksrcb[it], &Ks[0][koff[it]]);
    gload_lds16(vsrcb[it], &Vs[0][voff[it]]);
  }

  for (int st = 0; st < 32; ++st) {
    const int cur = st & 1;
    __syncthreads();  // drains tile-st loads; all waves done with buf[cur^1]
    if (st < 31) {
      const int s1 = (st + 1) * 64;
#pragma unroll
      for (int it = 0; it < 2; ++it) {
        gload_lds16(ksrcb[it] + (size_t)s1 * NQKV, &Ks[cur ^ 1][koff[it]]);
        gload_lds16(vsrcb[it] + s1, &Vs[cur ^ 1][voff[it]]);
      }
    }

    // S^T = K Q^T : sa[c][r] = S[s = c*16 + l4*4 + r][q = l15]  (k1-scaled)
    f32x4 sa[4];
#pragma unroll
    for (int c = 0; c < 4; ++c) {
      sa[c] = zero;
      int srow = c * 16 + l15;
      int sw = srow & 7;
#pragma unroll
      for (int ks = 0; ks < 4; ++ks) {
        bf16x8 kf = *(const bf16x8*)&Ks[cur][srow * 128 + (((ks * 4 + l4) ^ sw) << 3)];
        sa[c] = __builtin_amdgcn_mfma_f32_16x16x32_bf16(kf, qf[ks], sa[c], 0, 0, 0);
      }
    }

    // lane-local online softmax (each lane owns q = l15 across 16 s-values)
    float pmax = sa[0][0];
#pragma unroll
    for (int c = 0; c < 4; ++c)
#pragma unroll
      for (int r = 0; r < 4; ++r) pmax = fmaxf(pmax, sa[c][r]);
    pmax = fmaxf(pmax, __shfl_xor(pmax, 16));
    pmax = fmaxf(pmax, __shfl_xor(pmax, 32));

    if (!__all(pmax - m_s <= 8.0f)) {  // defer-max: rescale only on real growth
      float mn = fmaxf(m_s, pmax);
      float al = exp2f(m_s - mn);
      m_s = mn;
      l_s *= al;
      float ar[4];
#pragma unroll
      for (int r = 0; r < 4; ++r) ar[r] = __shfl(al, l4 * 4 + r);
#pragma unroll
      for (int nb = 0; nb < 8; ++nb)
#pragma unroll
        for (int r = 0; r < 4; ++r) o[nb][r] *= ar[r];
    }

    float ps = 0.f;
#pragma unroll
    for (int c = 0; c < 4; ++c)
#pragma unroll
      for (int r = 0; r < 4; ++r) {
        float p = exp2f(sa[c][r] - m_s);
        sa[c][r] = p;
        ps += p;
      }
    ps += __shfl_xor(ps, 16);
    ps += __shfl_xor(ps, 32);
    l_s += ps;

    // pack P to bf16 pairs, then redistribute C-frag -> A-frag via shfl
    int pk0[2], pk1[2], pk2[2], pk3[2];
    pk0[0] = cvtpk_bf16(sa[0][0], sa[0][1]); pk0[1] = cvtpk_bf16(sa[0][2], sa[0][3]);
    pk1[0] = cvtpk_bf16(sa[1][0], sa[1][1]); pk1[1] = cvtpk_bf16(sa[1][2], sa[1][3]);
    pk2[0] = cvtpk_bf16(sa[2][0], sa[2][1]); pk2[1] = cvtpk_bf16(sa[2][2], sa[2][3]);
    pk3[0] = cvtpk_bf16(sa[3][0], sa[3][1]); pk3[1] = cvtpk_bf16(sa[3][2], sa[3][3]);

    const int srcA = ((lane >> 4) & 1) * 32 + l15;  // lanes holding s-quads for this dest
    const int srcB = srcA + 16;
    const bool cHi = lane >= 32;  // dest c-block select (c = l4>>1)

    int a00 = __shfl(pk0[0], srcA), a01 = __shfl(pk0[1], srcA);
    int a02 = __shfl(pk0[0], srcB), a03 = __shfl(pk0[1], srcB);
    int b00 = __shfl(pk1[0], srcA), b01 = __shfl(pk1[1], srcA);
    int b02 = __shfl(pk1[0], srcB), b03 = __shfl(pk1[1], srcB);
    bf16x8 pa0 = mkfrag(cHi ? b00 : a00, cHi ? b01 : a01,
                        cHi ? b02 : a02, cHi ? b03 : a03);

    int a10 = __shfl(pk2[0], srcA), a11 = __shfl(pk2[1], srcA);
    int a12 = __shfl(pk2[0], srcB), a13 = __shfl(pk2[1], srcB);
    int b10 = __shfl(pk3[0], srcA), b11 = __shfl(pk3[1], srcA);
    int b12 = __shfl(pk3[0], srcB), b13 = __shfl(pk3[1], srcB);
    bf16x8 pa1 = mkfrag(cHi ? b10 : a10, cHi ? b11 : a11,
                        cHi ? b12 : a12, cHi ? b13 : a13);

    // PV: o[16 q][128 d] += P[16 q][64 s] * V[64 s][128 d]
#pragma unroll
    for (int nb = 0; nb < 8; ++nb) {
      int vrow = nb * 16 + l15;
      int sw = vrow & 7;
      bf16x8 vb0 = *(const bf16x8*)&Vs[cur][vrow * 64 + ((l4 ^ sw) << 3)];
      o[nb] = __builtin_amdgcn_mfma_f32_16x16x32_bf16(pa0, vb0, o[nb], 0, 0, 0);
      bf16x8 vb1 = *(const bf16x8*)&Vs[cur][vrow * 64 + (((4 + l4) ^ sw) << 3)];
      o[nb] = __builtin_amdgcn_mfma_f32_16x16x32_bf16(pa1, vb1, o[nb], 0, 0, 0);
    }
  }

  // epilogue: y[token][h*128 + d] = o / l
  float lr[4];
#pragma unroll
  for (int r = 0; r < 4; ++r) lr[r] = __shfl(l_s, l4 * 4 + r);
#pragma unroll
  for (int nb = 0; nb < 8; ++nb) {
#pragma unroll
    for (int r = 0; r < 4; ++r) {
      int qrow = tb + q0 + l4 * 4 + r;
      y[(size_t)qrow * C_ + h * DH_ + nb * 16 + l15] = f2bf(o[nb][r] / lr[r]);
    }
  }
}

// ---------------- launch ----------------------------------------------------
extern "C" void kernel_launch(void* const* d_in, const int* in_sizes, int n_in,
                              void* d_out, int out_size, void* d_ws, size_t ws_size,
                              hipStream_t stream) {
  (void)in_sizes; (void)n_in; (void)out_size; (void)ws_size;
  const void* x  = d_in[0];
  const void* Wq = d_in[1];
  const void* Wk = d_in[2];
  const void* Wv = d_in[3];
  const void* Wo = d_in[4];

  char* ws = (char*)d_ws;
  ushort_t* xb  = (ushort_t*)(ws + OFF_XB);   // also reused as y
  ushort_t* WT  = (ushort_t*)(ws + OFF_WT);
  ushort_t* WoT = (ushort_t*)(ws + OFF_WOT);
  ushort_t* qkv = (ushort_t*)(ws + OFF_QKV);
  ushort_t* vTp = (ushort_t*)(ws + OFF_VT);
  int* flag     = (int*)(ws + OFF_FLAG);

  detect_dtype<<<1, 1, 0, stream>>>((const ushort_t*)x, flag);

  // x -> bf16
  cast_x<<<4096, 256, 0, stream>>>(x, xb, flag, (BT_ * C_) / 8);

  // weights -> transposed bf16
  transpose_cast<<<dim3(64, 64), 256, 0, stream>>>(Wq, WT, flag, 2048, 2048, 2048, 0);
  transpose_cast<<<dim3(4, 64), 256, 0, stream>>>(Wk, WT, flag, 2048, 128, 2048, 2048);
  transpose_cast<<<dim3(4, 64), 256, 0, stream>>>(Wv, WT, flag, 2048, 128, 2048, 2176);
  transpose_cast<<<dim3(64, 64), 256, 0, stream>>>(Wo, WoT, flag, 2048, 2048, 2048, 0);

  // qkv = xb @ WT^T ; q columns pre-scaled by 1/sqrt(128)*log2(e) for exp2 softmax
  const float k1 = 0.08838834764831845f * 1.4426950408889634f;
  gemm_bt<<<dim3(NQKV / 128, BT_ / 128), 256, 0, stream>>>(xb, WT, qkv, BT_, NQKV, C_, 0, flag, k1, 2048);

  // v -> vT
  transpose_v<<<dim3(T_ / 32, DH_ / 32, B_), 256, 0, stream>>>(qkv, vTp);

  // attention -> y (reuses xb buffer), MQA: K/V shared across 2 heads/block
  attn_kernel<<<dim3(T_ / 64, H_ / 2, B_), 512, 0, stream>>>(qkv, vTp, xb);

  // out = y @ WoT^T
  gemm_bt<<<dim3(C_ / 128, BT_ / 128), 256, 0, stream>>>(xb, WoT, d_out, BT_, C_, C_, 1, flag, 1.0f, 0);
}

// Round 5
// 345.180 us; speedup vs baseline: 1.5476x; 1.0522x over previous
//
#include <hip/hip_runtime.h>

typedef unsigned short ushort_t;
typedef short bf16x8 __attribute__((ext_vector_type(8)));
typedef float f32x4 __attribute__((ext_vector_type(4)));

#define B_    2
#define T_    2048
#define C_    2048
#define H_    16
#define DH_   128
#define BT_   4096
#define NQKV  2304

// workspace offsets (bytes), all 256-aligned
#define OFF_XB   0UL            // xb (bf16 x) [4096][2048] ; reused as y after attention
#define OFF_WT   16777216UL     // WT_all [2304][2048] bf16
#define OFF_WOT  26214400UL     // WoT [2048][2048] bf16
#define OFF_QKV  34603008UL     // qkv [4096][2304] bf16 (q cols pre-scaled by 1/sqrt(128)*log2e)
#define OFF_VT   53477376UL     // vT [2][128][2048] bf16
#define OFF_FLAG 54525952UL     // int flag: 1 = inputs are bf16, 0 = fp32

__device__ __forceinline__ ushort_t f2bf(float f) {
  union { float f; unsigned u; } v; v.f = f;
  unsigned r = v.u + 0x7fffu + ((v.u >> 16) & 1u);
  return (ushort_t)(r >> 16);
}
__device__ __forceinline__ float bf2f(ushort_t u) {
  union { float f; unsigned u; } v; v.u = ((unsigned)u) << 16;
  return v.f;
}
__device__ __forceinline__ int cvtpk_bf16(float lo, float hi) {
  int r;
  asm("v_cvt_pk_bf16_f32 %0, %1, %2" : "=v"(r) : "v"(lo), "v"(hi));
  return r;
}
__device__ __forceinline__ bf16x8 mkfrag(int d0, int d1, int d2, int d3) {
  union { int i[4]; bf16x8 v; } u;
  u.i[0] = d0; u.i[1] = d1; u.i[2] = d2; u.i[3] = d3;
  return u.v;
}

__device__ __forceinline__ void gload_lds16(const ushort_t* g, ushort_t* l) {
  __builtin_amdgcn_global_load_lds((__attribute__((address_space(1))) void*)g,
                                   (__attribute__((address_space(3))) void*)l,
                                   16, 0, 0);
}

// ---------------- dtype detector -------------------------------------------
__global__ void detect_dtype(const ushort_t* x, int* flag) {
  if (threadIdx.x == 0 && blockIdx.x == 0) {
    int sane = 0;
    for (int i = 0; i < 32; ++i) {
      ushort_t u = x[2 * i];
      int e = (u >> 7) & 0xFF;
      if (u == 0 || (e >= 100 && e <= 140)) ++sane;
    }
    *flag = (sane >= 24) ? 1 : 0;
  }
}

// ---------------- cast x -> bf16 -------------------------------------------
__global__ __launch_bounds__(256) void cast_x(const void* __restrict__ xin,
                                              ushort_t* __restrict__ xb,
                                              const int* __restrict__ flag, int n8) {
  int i = blockIdx.x * 256 + threadIdx.x;
  if (i >= n8) return;
  if (*flag) {
    *(bf16x8*)(xb + (size_t)i * 8) = *(const bf16x8*)((const ushort_t*)xin + (size_t)i * 8);
  } else {
    const float* xf = (const float*)xin;
    f32x4 a = *(const f32x4*)(xf + (size_t)i * 8);
    f32x4 b = *(const f32x4*)(xf + (size_t)i * 8 + 4);
    bf16x8 o;
    o[0] = (short)f2bf(a[0]); o[1] = (short)f2bf(a[1]);
    o[2] = (short)f2bf(a[2]); o[3] = (short)f2bf(a[3]);
    o[4] = (short)f2bf(b[0]); o[5] = (short)f2bf(b[1]);
    o[6] = (short)f2bf(b[2]); o[7] = (short)f2bf(b[3]);
    *(bf16x8*)(xb + (size_t)i * 8) = o;
  }
}

// ---------------- transpose+cast weight: dst[row_off+c][r] = src[r][c] -----
__global__ __launch_bounds__(256) void transpose_cast(const void* __restrict__ src,
                                                      ushort_t* __restrict__ dst,
                                                      const int* __restrict__ flag,
                                                      int rows, int cols, int dst_ld,
                                                      int dst_row_off) {
  __shared__ float tile[32][33];
  int c0 = blockIdx.x * 32, r0 = blockIdx.y * 32;
  int tx = threadIdx.x & 31, ty = threadIdx.x >> 5;  // 32 x 8
  bool isbf = (*flag != 0);
#pragma unroll
  for (int j = 0; j < 4; ++j) {
    int r = r0 + ty + j * 8;
    float v;
    if (isbf) v = bf2f(((const ushort_t*)src)[(size_t)r * cols + c0 + tx]);
    else      v = ((const float*)src)[(size_t)r * cols + c0 + tx];
    tile[ty + j * 8][tx] = v;
  }
  __syncthreads();
#pragma unroll
  for (int j = 0; j < 4; ++j) {
    int c = c0 + ty + j * 8;
    dst[(size_t)(dst_row_off + c) * dst_ld + r0 + tx] = f2bf(tile[tx][ty + j * 8]);
  }
}

// ---------------- transpose v slice of qkv -> vT (bf16) --------------------
__global__ __launch_bounds__(256) void transpose_v(const ushort_t* __restrict__ qkv,
                                                   ushort_t* __restrict__ vT) {
  __shared__ ushort_t tile[32][33];
  int b = blockIdx.z;
  int t0 = blockIdx.x * 32, d0 = blockIdx.y * 32;
  int tx = threadIdx.x & 31, ty = threadIdx.x >> 5;
#pragma unroll
  for (int j = 0; j < 4; ++j) {
    int t = t0 + ty + j * 8;
    tile[ty + j * 8][tx] = qkv[(size_t)(b * T_ + t) * NQKV + 2176 + d0 + tx];
  }
  __syncthreads();
#pragma unroll
  for (int j = 0; j < 4; ++j) {
    int d = d0 + ty + j * 8;
    vT[(size_t)b * (DH_ * T_) + (size_t)d * T_ + t0 + tx] = tile[tx][ty + j * 8];
  }
}

// ---------------- GEMM: C[m][n] = sum_k A[m][k] * Bt[n][k]  (bf16 MFMA) ----
// 128x128 tile, BK=32, 256 threads = 4 waves (2x2), each wave 64x64.
// v2: double-buffered LDS + counted vmcnt(4) + raw barriers (loads stay in
// flight across barriers); bijective XCD swizzle for A-panel L2 locality.
__global__ __launch_bounds__(256) void gemm_bt(const ushort_t* __restrict__ A,
                                               const ushort_t* __restrict__ Bt,
                                               void* __restrict__ Cv,
                                               int M, int N, int K,
                                               int is_final, const int* __restrict__ flag,
                                               float qscale, int qcols) {
  __shared__ __align__(16) ushort_t As[2][128 * 32];
  __shared__ __align__(16) ushort_t Bs[2][128 * 32];
  const int tid = threadIdx.x;
  const int lane = tid & 63;
  const int wid = tid >> 6;

  // bijective XCD swizzle (m204): contiguous grid chunk per XCD
  const int gx = gridDim.x;
  const int nwg = gx * gridDim.y;
  const int orig = blockIdx.y * gx + blockIdx.x;
  const int qq = nwg >> 3, rr = nwg & 7;
  const int xcd = orig & 7, pos = orig >> 3;
  const int wg = (xcd < rr ? xcd * (qq + 1) : rr * (qq + 1) + (xcd - rr) * qq) + pos;
  const int bx = wg % gx, by = wg / gx;

  const int m0 = by * 128;
  const int n0 = bx * 128;
  const int wr = wid >> 1, wc = wid & 1;
  const int l15 = lane & 15, l4 = lane >> 4;

  f32x4 zero = {0.f, 0.f, 0.f, 0.f};
  f32x4 acc[4][4];
#pragma unroll
  for (int r = 0; r < 4; ++r)
#pragma unroll
    for (int c = 0; c < 4; ++c) acc[r][c] = zero;

  const ushort_t* ga = A + (size_t)(m0 + (tid >> 2)) * K + (tid & 3) * 8;
  const ushort_t* gb = Bt + (size_t)(n0 + (tid >> 2)) * K + (tid & 3) * 8;
  const size_t stride64 = (size_t)64 * K;
  const int lofs = wid * 512;  // wave-uniform LDS base (elements)

  // prologue: stage tile 0 into buffer 0
  gload_lds16(ga, As[0] + lofs);
  gload_lds16(ga + stride64, As[0] + lofs + 2048);
  gload_lds16(gb, Bs[0] + lofs);
  gload_lds16(gb + stride64, Bs[0] + lofs + 2048);

  const int NT = K >> 5;
  for (int t = 0; t < NT; ++t) {
    const int cur = t & 1;
    if (t + 1 < NT) {
      const int k1 = (t + 1) << 5;
      gload_lds16(ga + k1, As[cur ^ 1] + lofs);
      gload_lds16(ga + k1 + stride64, As[cur ^ 1] + lofs + 2048);
      gload_lds16(gb + k1, Bs[cur ^ 1] + lofs);
      gload_lds16(gb + k1 + stride64, Bs[cur ^ 1] + lofs + 2048);
      asm volatile("s_waitcnt vmcnt(4)" ::: "memory");  // tile t landed; t+1 in flight
    } else {
      asm volatile("s_waitcnt vmcnt(0)" ::: "memory");
    }
    __builtin_amdgcn_s_barrier();  // whole tile t visible to all waves

    bf16x8 af[4], bfr[4];
#pragma unroll
    for (int r = 0; r < 4; ++r)
      af[r] = *(const bf16x8*)&As[cur][(wr * 64 + r * 16 + l15) * 32 + l4 * 8];
#pragma unroll
    for (int c = 0; c < 4; ++c)
      bfr[c] = *(const bf16x8*)&Bs[cur][(wc * 64 + c * 16 + l15) * 32 + l4 * 8];
    __builtin_amdgcn_s_setprio(1);
#pragma unroll
    for (int r = 0; r < 4; ++r)
#pragma unroll
      for (int c = 0; c < 4; ++c)
        acc[r][c] = __builtin_amdgcn_mfma_f32_16x16x32_bf16(af[r], bfr[c], acc[r][c], 0, 0, 0);
    __builtin_amdgcn_s_setprio(0);
    __builtin_amdgcn_s_barrier();  // all waves done reading buf[cur]; next iter overwrites it
  }

  const bool f32out = is_final && (*flag == 0);
#pragma unroll
  for (int r = 0; r < 4; ++r) {
#pragma unroll
    for (int c = 0; c < 4; ++c) {
      int row = m0 + wr * 64 + r * 16 + l4 * 4;
      int col = n0 + wc * 64 + c * 16 + l15;
      float s = (col < qcols) ? qscale : 1.0f;
#pragma unroll
      for (int g = 0; g < 4; ++g) {
        float v = acc[r][c][g] * s;
        if (f32out) ((float*)Cv)[(size_t)(row + g) * N + col] = v;
        else ((ushort_t*)Cv)[(size_t)(row + g) * N + col] = f2bf(v);
      }
    }
  }
}

// ---------------- flash attention (v4: 32 q-rows/wave) ----------------------
// grid (16 qtiles, 8 head-pairs, 2 batches) = 256 blocks, 512 threads = 8 waves.
// Waves 0-3 -> head 2*by, waves 4-7 -> head 2*by+1; each wave: 32 q-rows as
// two 16-row groups g=0,1 SHARING the K/V LDS fragments (halves LDS read BW
// per MFMA). Double-buffered K [64][128] / V^T [128][64] tiles (XOR-swizzled),
// staged via global_load_lds with pre-swizzled global source; one barrier/step.
// Swapped QK^T -> lane-local softmax; P via cvt_pk + shfl (no P LDS);
// defer-max THR=8 in exp2 domain (Q pre-scaled by 1/sqrt(128)*log2e).
__global__ __launch_bounds__(512, 2) void attn_kernel(const ushort_t* __restrict__ qkv,
                                                      const ushort_t* __restrict__ vT,
                                                      ushort_t* __restrict__ y) {
  __shared__ __align__(16) ushort_t Ks[2][64 * 128];
  __shared__ __align__(16) ushort_t Vs[2][128 * 64];

  const int tid = threadIdx.x;
  const int lane = tid & 63;
  const int wid = tid >> 6;                 // 0..7
  const int h = blockIdx.y * 2 + (wid >> 2);
  const int b = blockIdx.z;
  const int tb = b * T_;
  const int q0 = blockIdx.x * 128 + (wid & 3) * 32;
  const int l15 = lane & 15, l4 = lane >> 4;

  // Q fragments for both 16-row groups (pre-scaled in GEMM1 epilogue)
  bf16x8 qf0[4], qf1[4];
  {
    const ushort_t* qb0 = qkv + (size_t)(tb + q0 + l15) * NQKV + h * DH_ + l4 * 8;
    const ushort_t* qb1 = qb0 + (size_t)16 * NQKV;
#pragma unroll
    for (int ks = 0; ks < 4; ++ks) {
      qf0[ks] = *(const bf16x8*)(qb0 + ks * 32);
      qf1[ks] = *(const bf16x8*)(qb1 + ks * 32);
    }
  }

  // staging addresses (pre-swizzled global source, linear LDS dest)
  const ushort_t* ksrcb[2];
  const ushort_t* vsrcb[2];
  int koff[2], voff[2];
#pragma unroll
  for (int it = 0; it < 2; ++it) {
    int id = tid + it * 512;
    int krow = id >> 4, kslot = id & 15;
    ksrcb[it] = qkv + (size_t)(tb + krow) * NQKV + 2048 + ((kslot ^ (krow & 7)) << 3);
    int vrow = id >> 3, vslot = id & 7;
    vsrcb[it] = vT + (size_t)b * (DH_ * T_) + (size_t)vrow * T_ + ((vslot ^ (vrow & 7)) << 3);
    koff[it] = (it * 512 + (wid << 6)) * 8;  // wave-uniform within buffer
    voff[it] = (it * 512 + (wid << 6)) * 8;
  }

  f32x4 zero = {0.f, 0.f, 0.f, 0.f};
  f32x4 o0[8], o1[8];
#pragma unroll
  for (int i = 0; i < 8; ++i) { o0[i] = zero; o1[i] = zero; }
  float m0s = -1e30f, m1s = -1e30f;
  float l0s = 0.f, l1s = 0.f;

  // prologue: stage tile 0 into buffer 0
#pragma unroll
  for (int it = 0; it < 2; ++it) {
    gload_lds16(ksrcb[it], &Ks[0][koff[it]]);
    gload_lds16(vsrcb[it], &Vs[0][voff[it]]);
  }

  for (int st = 0; st < 32; ++st) {
    const int cur = st & 1;
    __syncthreads();  // drains tile-st loads (aged one full step); buf[cur^1] free
    if (st < 31) {
      const int s1 = (st + 1) * 64;
#pragma unroll
      for (int it = 0; it < 2; ++it) {
        gload_lds16(ksrcb[it] + (size_t)s1 * NQKV, &Ks[cur ^ 1][koff[it]]);
        gload_lds16(vsrcb[it] + s1, &Vs[cur ^ 1][voff[it]]);
      }
    }

    // S^T = K Q^T for both q-groups, sharing kf fragments
    f32x4 sa0[4], sa1[4];
    __builtin_amdgcn_s_setprio(1);
#pragma unroll
    for (int c = 0; c < 4; ++c) {
      int srow = c * 16 + l15;
      int sw = srow & 7;
      bf16x8 kf[4];
#pragma unroll
      for (int ks = 0; ks < 4; ++ks)
        kf[ks] = *(const bf16x8*)&Ks[cur][srow * 128 + (((ks * 4 + l4) ^ sw) << 3)];
      sa0[c] = zero; sa1[c] = zero;
#pragma unroll
      for (int ks = 0; ks < 4; ++ks) {
        sa0[c] = __builtin_amdgcn_mfma_f32_16x16x32_bf16(kf[ks], qf0[ks], sa0[c], 0, 0, 0);
        sa1[c] = __builtin_amdgcn_mfma_f32_16x16x32_bf16(kf[ks], qf1[ks], sa1[c], 0, 0, 0);
      }
    }
    __builtin_amdgcn_s_setprio(0);

    // ---- lane-local online softmax, group 0 ----
    float pmax0 = sa0[0][0];
#pragma unroll
    for (int c = 0; c < 4; ++c)
#pragma unroll
      for (int r = 0; r < 4; ++r) pmax0 = fmaxf(pmax0, sa0[c][r]);
    pmax0 = fmaxf(pmax0, __shfl_xor(pmax0, 16));
    pmax0 = fmaxf(pmax0, __shfl_xor(pmax0, 32));
    if (!__all(pmax0 - m0s <= 8.0f)) {
      float mn = fmaxf(m0s, pmax0);
      float al = exp2f(m0s - mn);
      m0s = mn; l0s *= al;
      float ar[4];
#pragma unroll
      for (int r = 0; r < 4; ++r) ar[r] = __shfl(al, l4 * 4 + r);
#pragma unroll
      for (int nb = 0; nb < 8; ++nb)
#pragma unroll
        for (int r = 0; r < 4; ++r) o0[nb][r] *= ar[r];
    }
    float ps0 = 0.f;
#pragma unroll
    for (int c = 0; c < 4; ++c)
#pragma unroll
      for (int r = 0; r < 4; ++r) {
        float p = exp2f(sa0[c][r] - m0s);
        sa0[c][r] = p;
        ps0 += p;
      }
    ps0 += __shfl_xor(ps0, 16);
    ps0 += __shfl_xor(ps0, 32);
    l0s += ps0;

    // ---- group 1 ----
    float pmax1 = sa1[0][0];
#pragma unroll
    for (int c = 0; c < 4; ++c)
#pragma unroll
      for (int r = 0; r < 4; ++r) pmax1 = fmaxf(pmax1, sa1[c][r]);
    pmax1 = fmaxf(pmax1, __shfl_xor(pmax1, 16));
    pmax1 = fmaxf(pmax1, __shfl_xor(pmax1, 32));
    if (!__all(pmax1 - m1s <= 8.0f)) {
      float mn = fmaxf(m1s, pmax1);
      float al = exp2f(m1s - mn);
      m1s = mn; l1s *= al;
      float ar[4];
#pragma unroll
      for (int r = 0; r < 4; ++r) ar[r] = __shfl(al, l4 * 4 + r);
#pragma unroll
      for (int nb = 0; nb < 8; ++nb)
#pragma unroll
        for (int r = 0; r < 4; ++r) o1[nb][r] *= ar[r];
    }
    float ps1 = 0.f;
#pragma unroll
    for (int c = 0; c < 4; ++c)
#pragma unroll
      for (int r = 0; r < 4; ++r) {
        float p = exp2f(sa1[c][r] - m1s);
        sa1[c][r] = p;
        ps1 += p;
      }
    ps1 += __shfl_xor(ps1, 16);
    ps1 += __shfl_xor(ps1, 32);
    l1s += ps1;

    // ---- P pack + C-frag -> A-frag redistribution (per group) ----
    const int srcA = ((lane >> 4) & 1) * 32 + l15;
    const int srcB = srcA + 16;
    const bool cHi = lane >= 32;

    bf16x8 g0pa0, g0pa1, g1pa0, g1pa1;
    {
      int pk0[2], pk1[2], pk2[2], pk3[2];
      pk0[0] = cvtpk_bf16(sa0[0][0], sa0[0][1]); pk0[1] = cvtpk_bf16(sa0[0][2], sa0[0][3]);
      pk1[0] = cvtpk_bf16(sa0[1][0], sa0[1][1]); pk1[1] = cvtpk_bf16(sa0[1][2], sa0[1][3]);
      pk2[0] = cvtpk_bf16(sa0[2][0], sa0[2][1]); pk2[1] = cvtpk_bf16(sa0[2][2], sa0[2][3]);
      pk3[0] = cvtpk_bf16(sa0[3][0], sa0[3][1]); pk3[1] = cvtpk_bf16(sa0[3][2], sa0[3][3]);
      int a00 = __shfl(pk0[0], srcA), a01 = __shfl(pk0[1], srcA);
      int a02 = __shfl(pk0[0], srcB), a03 = __shfl(pk0[1], srcB);
      int b00 = __shfl(pk1[0], srcA), b01 = __shfl(pk1[1], srcA);
      int b02 = __shfl(pk1[0], srcB), b03 = __shfl(pk1[1], srcB);
      g0pa0 = mkfrag(cHi ? b00 : a00, cHi ? b01 : a01, cHi ? b02 : a02, cHi ? b03 : a03);
      int a10 = __shfl(pk2[0], srcA), a11 = __shfl(pk2[1], srcA);
      int a12 = __shfl(pk2[0], srcB), a13 = __shfl(pk2[1], srcB);
      int b10 = __shfl(pk3[0], srcA), b11 = __shfl(pk3[1], srcA);
      int b12 = __shfl(pk3[0], srcB), b13 = __shfl(pk3[1], srcB);
      g0pa1 = mkfrag(cHi ? b10 : a10, cHi ? b11 : a11, cHi ? b12 : a12, cHi ? b13 : a13);
    }
    {
      int pk0[2], pk1[2], pk2[2], pk3[2];
      pk0[0] = cvtpk_bf16(sa1[0][0], sa1[0][1]); pk0[1] = cvtpk_bf16(sa1[0][2], sa1[0][3]);
      pk1[0] = cvtpk_bf16(sa1[1][0], sa1[1][1]); pk1[1] = cvtpk_bf16(sa1[1][2], sa1[1][3]);
      pk2[0] = cvtpk_bf16(sa1[2][0], sa1[2][1]); pk2[1] = cvtpk_bf16(sa1[2][2], sa1[2][3]);
      pk3[0] = cvtpk_bf16(sa1[3][0], sa1[3][1]); pk3[1] = cvtpk_bf16(sa1[3][2], sa1[3][3]);
      int a00 = __shfl(pk0[0], srcA), a01 = __shfl(pk0[1], srcA);
      int a02 = __shfl(pk0[0], srcB), a03 = __shfl(pk0[1], srcB);
      int b00 = __shfl(pk1[0], srcA), b01 = __shfl(pk1[1], srcA);
      int b02 = __shfl(pk1[0], srcB), b03 = __shfl(pk1[1], srcB);
      g1pa0 = mkfrag(cHi ? b00 : a00, cHi ? b01 : a01, cHi ? b02 : a02, cHi ? b03 : a03);
      int a10 = __shfl(pk2[0], srcA), a11 = __shfl(pk2[1], srcA);
      int a12 = __shfl(pk2[0], srcB), a13 = __shfl(pk2[1], srcB);
      int b10 = __shfl(pk3[0], srcA), b11 = __shfl(pk3[1], srcA);
      int b12 = __shfl(pk3[0], srcB), b13 = __shfl(pk3[1], srcB);
      g1pa1 = mkfrag(cHi ? b10 : a10, cHi ? b11 : a11, cHi ? b12 : a12, cHi ? b13 : a13);
    }

    // PV: both groups share vb fragments
    __builtin_amdgcn_s_setprio(1);
#pragma unroll
    for (int nb = 0; nb < 8; ++nb) {
      int vrow = nb * 16 + l15;
      int sw = vrow & 7;
      bf16x8 vb0 = *(const bf16x8*)&Vs[cur][vrow * 64 + ((l4 ^ sw) << 3)];
      o0[nb] = __builtin_amdgcn_mfma_f32_16x16x32_bf16(g0pa0, vb0, o0[nb], 0, 0, 0);
      o1[nb] = __builtin_amdgcn_mfma_f32_16x16x32_bf16(g1pa0, vb0, o1[nb], 0, 0, 0);
      bf16x8 vb1 = *(const bf16x8*)&Vs[cur][vrow * 64 + (((4 + l4) ^ sw) << 3)];
      o0[nb] = __builtin_amdgcn_mfma_f32_16x16x32_bf16(g0pa1, vb1, o0[nb], 0, 0, 0);
      o1[nb] = __builtin_amdgcn_mfma_f32_16x16x32_bf16(g1pa1, vb1, o1[nb], 0, 0, 0);
    }
    __builtin_amdgcn_s_setprio(0);
  }

  // epilogue: y[token][h*128 + d] = o / l
  {
    float lr[4];
#pragma unroll
    for (int r = 0; r < 4; ++r) lr[r] = __shfl(l0s, l4 * 4 + r);
#pragma unroll
    for (int nb = 0; nb < 8; ++nb)
#pragma unroll
      for (int r = 0; r < 4; ++r) {
        int qrow = tb + q0 + l4 * 4 + r;
        y[(size_t)qrow * C_ + h * DH_ + nb * 16 + l15] = f2bf(o0[nb][r] / lr[r]);
      }
  }
  {
    float lr[4];
#pragma unroll
    for (int r = 0; r < 4; ++r) lr[r] = __shfl(l1s, l4 * 4 + r);
#pragma unroll
    for (int nb = 0; nb < 8; ++nb)
#pragma unroll
      for (int r = 0; r < 4; ++r) {
        int qrow = tb + q0 + 16 + l4 * 4 + r;
        y[(size_t)qrow * C_ + h * DH_ + nb * 16 + l15] = f2bf(o1[nb][r] / lr[r]);
      }
  }
}

// ---------------- launch ----------------------------------------------------
extern "C" void kernel_launch(void* const* d_in, const int* in_sizes, int n_in,
                              void* d_out, int out_size, void* d_ws, size_t ws_size,
                              hipStream_t stream) {
  (void)in_sizes; (void)n_in; (void)out_size; (void)ws_size;
  const void* x  = d_in[0];
  const void* Wq = d_in[1];
  const void* Wk = d_in[2];
  const void* Wv = d_in[3];
  const void* Wo = d_in[4];

  char* ws = (char*)d_ws;
  ushort_t* xb  = (ushort_t*)(ws + OFF_XB);   // also reused as y
  ushort_t* WT  = (ushort_t*)(ws + OFF_WT);
  ushort_t* WoT = (ushort_t*)(ws + OFF_WOT);
  ushort_t* qkv = (ushort_t*)(ws + OFF_QKV);
  ushort_t* vTp = (ushort_t*)(ws + OFF_VT);
  int* flag     = (int*)(ws + OFF_FLAG);

  detect_dtype<<<1, 1, 0, stream>>>((const ushort_t*)x, flag);

  // x -> bf16
  cast_x<<<4096, 256, 0, stream>>>(x, xb, flag, (BT_ * C_) / 8);

  // weights -> transposed bf16
  transpose_cast<<<dim3(64, 64), 256, 0, stream>>>(Wq, WT, flag, 2048, 2048, 2048, 0);
  transpose_cast<<<dim3(4, 64), 256, 0, stream>>>(Wk, WT, flag, 2048, 128, 2048, 2048);
  transpose_cast<<<dim3(4, 64), 256, 0, stream>>>(Wv, WT, flag, 2048, 128, 2048, 2176);
  transpose_cast<<<dim3(64, 64), 256, 0, stream>>>(Wo, WoT, flag, 2048, 2048, 2048, 0);

  // qkv = xb @ WT^T ; q columns pre-scaled by 1/sqrt(128)*log2(e) for exp2 softmax
  const float k1 = 0.08838834764831845f * 1.4426950408889634f;
  gemm_bt<<<dim3(NQKV / 128, BT_ / 128), 256, 0, stream>>>(xb, WT, qkv, BT_, NQKV, C_, 0, flag, k1, 2048);

  // v -> vT
  transpose_v<<<dim3(T_ / 32, DH_ / 32, B_), 256, 0, stream>>>(qkv, vTp);

  // attention -> y (reuses xb buffer); MQA: K/V shared across 2 heads, 32 q/wave
  attn_kernel<<<dim3(T_ / 128, H_ / 2, B_), 512, 0, stream>>>(qkv, vTp, xb);

  // out = y @ WoT^T
  gemm_bt<<<dim3(C_ / 128, BT_ / 128), 256, 0, stream>>>(xb, WoT, d_out, BT_, C_, C_, 1, flag, 1.0f, 0);
}

// Round 7
// 344.750 us; speedup vs baseline: 1.5495x; 1.0012x over previous
//
#include <hip/hip_runtime.h>

typedef unsigned short ushort_t;
typedef short bf16x8 __attribute__((ext_vector_type(8)));
typedef float f32x4 __attribute__((ext_vector_type(4)));

#define B_    2
#define T_    2048
#define C_    2048
#define H_    16
#define DH_   128
#define BT_   4096
#define NQKV  2304

// workspace offsets (bytes), all 256-aligned
#define OFF_XB   0UL            // xb (bf16 x) [4096][2048] ; reused as y after attention
#define OFF_WT   16777216UL     // WT_all [2304][2048] bf16
#define OFF_WOT  26214400UL     // WoT [2048][2048] bf16
#define OFF_QKV  34603008UL     // qkv [4096][2304] bf16 (q cols pre-scaled by 1/sqrt(128)*log2e)
#define OFF_VT   53477376UL     // vT [2][128][2048] bf16
#define OFF_FLAG 54525952UL     // int flag: 1 = inputs are bf16, 0 = fp32

__device__ __forceinline__ ushort_t f2bf(float f) {
  union { float f; unsigned u; } v; v.f = f;
  unsigned r = v.u + 0x7fffu + ((v.u >> 16) & 1u);
  return (ushort_t)(r >> 16);
}
__device__ __forceinline__ float bf2f(ushort_t u) {
  union { float f; unsigned u; } v; v.u = ((unsigned)u) << 16;
  return v.f;
}
__device__ __forceinline__ int cvtpk_bf16(float lo, float hi) {
  int r;
  asm("v_cvt_pk_bf16_f32 %0, %1, %2" : "=v"(r) : "v"(lo), "v"(hi));
  return r;
}
__device__ __forceinline__ bf16x8 mkfrag(int d0, int d1, int d2, int d3) {
  union { int i[4]; bf16x8 v; } u;
  u.i[0] = d0; u.i[1] = d1; u.i[2] = d2; u.i[3] = d3;
  return u.v;
}

__device__ __forceinline__ void gload_lds16(const ushort_t* g, ushort_t* l) {
  __builtin_amdgcn_global_load_lds((__attribute__((address_space(1))) void*)g,
                                   (__attribute__((address_space(3))) void*)l,
                                   16, 0, 0);
}

// ---------------- dtype detector -------------------------------------------
__global__ void detect_dtype(const ushort_t* x, int* flag) {
  if (threadIdx.x == 0 && blockIdx.x == 0) {
    int sane = 0;
    for (int i = 0; i < 32; ++i) {
      ushort_t u = x[2 * i];
      int e = (u >> 7) & 0xFF;
      if (u == 0 || (e >= 100 && e <= 140)) ++sane;
    }
    *flag = (sane >= 24) ? 1 : 0;
  }
}

// ---------------- cast x -> bf16 -------------------------------------------
__global__ __launch_bounds__(256) void cast_x(const void* __restrict__ xin,
                                              ushort_t* __restrict__ xb,
                                              const int* __restrict__ flag, int n8) {
  int i = blockIdx.x * 256 + threadIdx.x;
  if (i >= n8) return;
  if (*flag) {
    *(bf16x8*)(xb + (size_t)i * 8) = *(const bf16x8*)((const ushort_t*)xin + (size_t)i * 8);
  } else {
    const float* xf = (const float*)xin;
    f32x4 a = *(const f32x4*)(xf + (size_t)i * 8);
    f32x4 b = *(const f32x4*)(xf + (size_t)i * 8 + 4);
    bf16x8 o;
    o[0] = (short)f2bf(a[0]); o[1] = (short)f2bf(a[1]);
    o[2] = (short)f2bf(a[2]); o[3] = (short)f2bf(a[3]);
    o[4] = (short)f2bf(b[0]); o[5] = (short)f2bf(b[1]);
    o[6] = (short)f2bf(b[2]); o[7] = (short)f2bf(b[3]);
    *(bf16x8*)(xb + (size_t)i * 8) = o;
  }
}

// ---------------- transpose+cast weight: dst[row_off+c][r] = src[r][c] -----
__global__ __launch_bounds__(256) void transpose_cast(const void* __restrict__ src,
                                                      ushort_t* __restrict__ dst,
                                                      const int* __restrict__ flag,
                                                      int rows, int cols, int dst_ld,
                                                      int dst_row_off) {
  __shared__ float tile[32][33];
  int c0 = blockIdx.x * 32, r0 = blockIdx.y * 32;
  int tx = threadIdx.x & 31, ty = threadIdx.x >> 5;  // 32 x 8
  bool isbf = (*flag != 0);
#pragma unroll
  for (int j = 0; j < 4; ++j) {
    int r = r0 + ty + j * 8;
    float v;
    if (isbf) v = bf2f(((const ushort_t*)src)[(size_t)r * cols + c0 + tx]);
    else      v = ((const float*)src)[(size_t)r * cols + c0 + tx];
    tile[ty + j * 8][tx] = v;
  }
  __syncthreads();
#pragma unroll
  for (int j = 0; j < 4; ++j) {
    int c = c0 + ty + j * 8;
    dst[(size_t)(dst_row_off + c) * dst_ld + r0 + tx] = f2bf(tile[tx][ty + j * 8]);
  }
}

// ---------------- transpose v slice of qkv -> vT (bf16) --------------------
__global__ __launch_bounds__(256) void transpose_v(const ushort_t* __restrict__ qkv,
                                                   ushort_t* __restrict__ vT) {
  __shared__ ushort_t tile[32][33];
  int b = blockIdx.z;
  int t0 = blockIdx.x * 32, d0 = blockIdx.y * 32;
  int tx = threadIdx.x & 31, ty = threadIdx.x >> 5;
#pragma unroll
  for (int j = 0; j < 4; ++j) {
    int t = t0 + ty + j * 8;
    tile[ty + j * 8][tx] = qkv[(size_t)(b * T_ + t) * NQKV + 2176 + d0 + tx];
  }
  __syncthreads();
#pragma unroll
  for (int j = 0; j < 4; ++j) {
    int d = d0 + ty + j * 8;
    vT[(size_t)b * (DH_ * T_) + (size_t)d * T_ + t0 + tx] = tile[tx][ty + j * 8];
  }
}

// ---------------- GEMM: C[m][n] = sum_k A[m][k] * Bt[n][k]  (bf16 MFMA) ----
// 128x128 tile, BK=32, 256 threads = 4 waves (2x2), each wave 64x64.
// Double-buffered LDS + counted vmcnt(4) + raw barriers; bijective XCD swizzle.
__global__ __launch_bounds__(256) void gemm_bt(const ushort_t* __restrict__ A,
                                               const ushort_t* __restrict__ Bt,
                                               void* __restrict__ Cv,
                                               int M, int N, int K,
                                               int is_final, const int* __restrict__ flag,
                                               float qscale, int qcols) {
  __shared__ __align__(16) ushort_t As[2][128 * 32];
  __shared__ __align__(16) ushort_t Bs[2][128 * 32];
  const int tid = threadIdx.x;
  const int lane = tid & 63;
  const int wid = tid >> 6;

  // bijective XCD swizzle (m204): contiguous grid chunk per XCD
  const int gx = gridDim.x;
  const int nwg = gx * gridDim.y;
  const int orig = blockIdx.y * gx + blockIdx.x;
  const int qq = nwg >> 3, rr = nwg & 7;
  const int xcd = orig & 7, pos = orig >> 3;
  const int wg = (xcd < rr ? xcd * (qq + 1) : rr * (qq + 1) + (xcd - rr) * qq) + pos;
  const int bx = wg % gx, by = wg / gx;

  const int m0 = by * 128;
  const int n0 = bx * 128;
  const int wr = wid >> 1, wc = wid & 1;
  const int l15 = lane & 15, l4 = lane >> 4;

  f32x4 zero = {0.f, 0.f, 0.f, 0.f};
  f32x4 acc[4][4];
#pragma unroll
  for (int r = 0; r < 4; ++r)
#pragma unroll
    for (int c = 0; c < 4; ++c) acc[r][c] = zero;

  const ushort_t* ga = A + (size_t)(m0 + (tid >> 2)) * K + (tid & 3) * 8;
  const ushort_t* gb = Bt + (size_t)(n0 + (tid >> 2)) * K + (tid & 3) * 8;
  const size_t stride64 = (size_t)64 * K;
  const int lofs = wid * 512;  // wave-uniform LDS base (elements)

  // prologue: stage tile 0 into buffer 0
  gload_lds16(ga, As[0] + lofs);
  gload_lds16(ga + stride64, As[0] + lofs + 2048);
  gload_lds16(gb, Bs[0] + lofs);
  gload_lds16(gb + stride64, Bs[0] + lofs + 2048);

  const int NT = K >> 5;
  for (int t = 0; t < NT; ++t) {
    const int cur = t & 1;
    if (t + 1 < NT) {
      const int k1 = (t + 1) << 5;
      gload_lds16(ga + k1, As[cur ^ 1] + lofs);
      gload_lds16(ga + k1 + stride64, As[cur ^ 1] + lofs + 2048);
      gload_lds16(gb + k1, Bs[cur ^ 1] + lofs);
      gload_lds16(gb + k1 + stride64, Bs[cur ^ 1] + lofs + 2048);
      asm volatile("s_waitcnt vmcnt(4)" ::: "memory");  // tile t landed; t+1 in flight
    } else {
      asm volatile("s_waitcnt vmcnt(0)" ::: "memory");
    }
    __builtin_amdgcn_s_barrier();  // whole tile t visible to all waves

    bf16x8 af[4], bfr[4];
#pragma unroll
    for (int r = 0; r < 4; ++r)
      af[r] = *(const bf16x8*)&As[cur][(wr * 64 + r * 16 + l15) * 32 + l4 * 8];
#pragma unroll
    for (int c = 0; c < 4; ++c)
      bfr[c] = *(const bf16x8*)&Bs[cur][(wc * 64 + c * 16 + l15) * 32 + l4 * 8];
    __builtin_amdgcn_s_setprio(1);
#pragma unroll
    for (int r = 0; r < 4; ++r)
#pragma unroll
      for (int c = 0; c < 4; ++c)
        acc[r][c] = __builtin_amdgcn_mfma_f32_16x16x32_bf16(af[r], bfr[c], acc[r][c], 0, 0, 0);
    __builtin_amdgcn_s_setprio(0);
    __builtin_amdgcn_s_barrier();  // all waves done reading buf[cur]
  }

  const bool f32out = is_final && (*flag == 0);
#pragma unroll
  for (int r = 0; r < 4; ++r) {
#pragma unroll
    for (int c = 0; c < 4; ++c) {
      int row = m0 + wr * 64 + r * 16 + l4 * 4;
      int col = n0 + wc * 64 + c * 16 + l15;
      float s = (col < qcols) ? qscale : 1.0f;
#pragma unroll
      for (int g = 0; g < 4; ++g) {
        float v = acc[r][c][g] * s;
        if (f32out) ((float*)Cv)[(size_t)(row + g) * N + col] = v;
        else ((ushort_t*)Cv)[(size_t)(row + g) * N + col] = f2bf(v);
      }
    }
  }
}

// ---------------- flash attention (v5b: 4-wave blocks, 2 blocks/CU) ---------
// grid (16 qtiles, 16 heads, 2 batches) = 512 blocks, 256 threads = 4 waves.
// One head per block; wave w covers q-rows [bx*128 + w*32, +32) as two
// 16-row groups sharing the wave's K/V LDS fragments. 2 blocks co-resident
// per CU (LDS 64KB each) -> independent barrier domains overlap stalls.
// K tile [64][128] AND V^T tile [128][64] are each 1024 16B-chunks ->
// 4 gload_lds issues/thread EACH at 256 threads (v5 bug: V had only 2).
// Double-buffered, XOR-swizzled, staged via global_load_lds with
// pre-swizzled global source; one barrier per KV step.
// Swapped QK^T -> lane-local softmax; P via cvt_pk + shfl (no P LDS);
// defer-max THR=8 in exp2 domain (Q pre-scaled by 1/sqrt(128)*log2e).
__global__ __launch_bounds__(256, 2) void attn_kernel(const ushort_t* __restrict__ qkv,
                                                      const ushort_t* __restrict__ vT,
                                                      ushort_t* __restrict__ y) {
  __shared__ __align__(16) ushort_t Ks[2][64 * 128];
  __shared__ __align__(16) ushort_t Vs[2][128 * 64];

  const int tid = threadIdx.x;
  const int lane = tid & 63;
  const int wid = tid >> 6;                 // 0..3
  const int h = blockIdx.y;
  const int b = blockIdx.z;
  const int tb = b * T_;
  const int q0 = blockIdx.x * 128 + wid * 32;
  const int l15 = lane & 15, l4 = lane >> 4;

  // Q fragments for both 16-row groups (pre-scaled in GEMM1 epilogue)
  bf16x8 qf0[4], qf1[4];
  {
    const ushort_t* qb0 = qkv + (size_t)(tb + q0 + l15) * NQKV + h * DH_ + l4 * 8;
    const ushort_t* qb1 = qb0 + (size_t)16 * NQKV;
#pragma unroll
    for (int ks = 0; ks < 4; ++ks) {
      qf0[ks] = *(const bf16x8*)(qb0 + ks * 32);
      qf1[ks] = *(const bf16x8*)(qb1 + ks * 32);
    }
  }

  // staging addresses (pre-swizzled global source, linear LDS dest)
  // K tile and V tile: 1024 16B-chunks each -> 4 per thread at 256 threads.
  const ushort_t* ksrcb[4];
  const ushort_t* vsrcb[4];
  int koff[4], voff[4];
#pragma unroll
  for (int it = 0; it < 4; ++it) {
    int id = tid + it * 256;
    int krow = id >> 4, kslot = id & 15;
    ksrcb[it] = qkv + (size_t)(tb + krow) * NQKV + 2048 + ((kslot ^ (krow & 7)) << 3);
    koff[it] = (it * 256 + (wid << 6)) * 8;  // wave-uniform within buffer
    int vrow = id >> 3, vslot = id & 7;
    vsrcb[it] = vT + (size_t)b * (DH_ * T_) + (size_t)vrow * T_ + ((vslot ^ (vrow & 7)) << 3);
    voff[it] = (it * 256 + (wid << 6)) * 8;
  }

  f32x4 zero = {0.f, 0.f, 0.f, 0.f};
  f32x4 o0[8], o1[8];
#pragma unroll
  for (int i = 0; i < 8; ++i) { o0[i] = zero; o1[i] = zero; }
  float m0s = -1e30f, m1s = -1e30f;
  float l0s = 0.f, l1s = 0.f;

  // prologue: stage tile 0 into buffer 0
#pragma unroll
  for (int it = 0; it < 4; ++it) {
    gload_lds16(ksrcb[it], &Ks[0][koff[it]]);
    gload_lds16(vsrcb[it], &Vs[0][voff[it]]);
  }

  for (int st = 0; st < 32; ++st) {
    const int cur = st & 1;
    __syncthreads();  // drains tile-st loads; buf[cur^1] free for prefetch
    if (st < 31) {
      const int s1 = (st + 1) * 64;
#pragma unroll
      for (int it = 0; it < 4; ++it) {
        gload_lds16(ksrcb[it] + (size_t)s1 * NQKV, &Ks[cur ^ 1][koff[it]]);
        gload_lds16(vsrcb[it] + s1, &Vs[cur ^ 1][voff[it]]);
      }
    }

    // S^T = K Q^T for both q-groups, sharing kf fragments
    f32x4 sa0[4], sa1[4];
    __builtin_amdgcn_s_setprio(1);
#pragma unroll
    for (int c = 0; c < 4; ++c) {
      int srow = c * 16 + l15;
      int sw = srow & 7;
      bf16x8 kf[4];
#pragma unroll
      for (int ks = 0; ks < 4; ++ks)
        kf[ks] = *(const bf16x8*)&Ks[cur][srow * 128 + (((ks * 4 + l4) ^ sw) << 3)];
      sa0[c] = zero; sa1[c] = zero;
#pragma unroll
      for (int ks = 0; ks < 4; ++ks) {
        sa0[c] = __builtin_amdgcn_mfma_f32_16x16x32_bf16(kf[ks], qf0[ks], sa0[c], 0, 0, 0);
        sa1[c] = __builtin_amdgcn_mfma_f32_16x16x32_bf16(kf[ks], qf1[ks], sa1[c], 0, 0, 0);
      }
    }
    __builtin_amdgcn_s_setprio(0);

    // ---- lane-local online softmax, group 0 ----
    float pmax0 = sa0[0][0];
#pragma unroll
    for (int c = 0; c < 4; ++c)
#pragma unroll
      for (int r = 0; r < 4; ++r) pmax0 = fmaxf(pmax0, sa0[c][r]);
    pmax0 = fmaxf(pmax0, __shfl_xor(pmax0, 16));
    pmax0 = fmaxf(pmax0, __shfl_xor(pmax0, 32));
    if (!__all(pmax0 - m0s <= 8.0f)) {
      float mn = fmaxf(m0s, pmax0);
      float al = exp2f(m0s - mn);
      m0s = mn; l0s *= al;
      float ar[4];
#pragma unroll
      for (int r = 0; r < 4; ++r) ar[r] = __shfl(al, l4 * 4 + r);
#pragma unroll
      for (int nb = 0; nb < 8; ++nb)
#pragma unroll
        for (int r = 0; r < 4; ++r) o0[nb][r] *= ar[r];
    }
    float ps0 = 0.f;
#pragma unroll
    for (int c = 0; c < 4; ++c)
#pragma unroll
      for (int r = 0; r < 4; ++r) {
        float p = exp2f(sa0[c][r] - m0s);
        sa0[c][r] = p;
        ps0 += p;
      }
    ps0 += __shfl_xor(ps0, 16);
    ps0 += __shfl_xor(ps0, 32);
    l0s += ps0;

    // ---- group 1 ----
    float pmax1 = sa1[0][0];
#pragma unroll
    for (int c = 0; c < 4; ++c)
#pragma unroll
      for (int r = 0; r < 4; ++r) pmax1 = fmaxf(pmax1, sa1[c][r]);
    pmax1 = fmaxf(pmax1, __shfl_xor(pmax1, 16));
    pmax1 = fmaxf(pmax1, __shfl_xor(pmax1, 32));
    if (!__all(pmax1 - m1s <= 8.0f)) {
      float mn = fmaxf(m1s, pmax1);
      float al = exp2f(m1s - mn);
      m1s = mn; l1s *= al;
      float ar[4];
#pragma unroll
      for (int r = 0; r < 4; ++r) ar[r] = __shfl(al, l4 * 4 + r);
#pragma unroll
      for (int nb = 0; nb < 8; ++nb)
#pragma unroll
        for (int r = 0; r < 4; ++r) o1[nb][r] *= ar[r];
    }
    float ps1 = 0.f;
#pragma unroll
    for (int c = 0; c < 4; ++c)
#pragma unroll
      for (int r = 0; r < 4; ++r) {
        float p = exp2f(sa1[c][r] - m1s);
        sa1[c][r] = p;
        ps1 += p;
      }
    ps1 += __shfl_xor(ps1, 16);
    ps1 += __shfl_xor(ps1, 32);
    l1s += ps1;

    // ---- P pack + C-frag -> A-frag redistribution (per group) ----
    const int srcA = ((lane >> 4) & 1) * 32 + l15;
    const int srcB = srcA + 16;
    const bool cHi = lane >= 32;

    bf16x8 g0pa0, g0pa1, g1pa0, g1pa1;
    {
      int pk0[2], pk1[2], pk2[2], pk3[2];
      pk0[0] = cvtpk_bf16(sa0[0][0], sa0[0][1]); pk0[1] = cvtpk_bf16(sa0[0][2], sa0[0][3]);
      pk1[0] = cvtpk_bf16(sa0[1][0], sa0[1][1]); pk1[1] = cvtpk_bf16(sa0[1][2], sa0[1][3]);
      pk2[0] = cvtpk_bf16(sa0[2][0], sa0[2][1]); pk2[1] = cvtpk_bf16(sa0[2][2], sa0[2][3]);
      pk3[0] = cvtpk_bf16(sa0[3][0], sa0[3][1]); pk3[1] = cvtpk_bf16(sa0[3][2], sa0[3][3]);
      int a00 = __shfl(pk0[0], srcA), a01 = __shfl(pk0[1], srcA);
      int a02 = __shfl(pk0[0], srcB), a03 = __shfl(pk0[1], srcB);
      int b00 = __shfl(pk1[0], srcA), b01 = __shfl(pk1[1], srcA);
      int b02 = __shfl(pk1[0], srcB), b03 = __shfl(pk1[1], srcB);
      g0pa0 = mkfrag(cHi ? b00 : a00, cHi ? b01 : a01, cHi ? b02 : a02, cHi ? b03 : a03);
      int a10 = __shfl(pk2[0], srcA), a11 = __shfl(pk2[1], srcA);
      int a12 = __shfl(pk2[0], srcB), a13 = __shfl(pk2[1], srcB);
      int b10 = __shfl(pk3[0], srcA), b11 = __shfl(pk3[1], srcA);
      int b12 = __shfl(pk3[0], srcB), b13 = __shfl(pk3[1], srcB);
      g0pa1 = mkfrag(cHi ? b10 : a10, cHi ? b11 : a11, cHi ? b12 : a12, cHi ? b13 : a13);
    }
    {
      int pk0[2], pk1[2], pk2[2], pk3[2];
      pk0[0] = cvtpk_bf16(sa1[0][0], sa1[0][1]); pk0[1] = cvtpk_bf16(sa1[0][2], sa1[0][3]);
      pk1[0] = cvtpk_bf16(sa1[1][0], sa1[1][1]); pk1[1] = cvtpk_bf16(sa1[1][2], sa1[1][3]);
      pk2[0] = cvtpk_bf16(sa1[2][0], sa1[2][1]); pk2[1] = cvtpk_bf16(sa1[2][2], sa1[2][3]);
      pk3[0] = cvtpk_bf16(sa1[3][0], sa1[3][1]); pk3[1] = cvtpk_bf16(sa1[3][2], sa1[3][3]);
      int a00 = __shfl(pk0[0], srcA), a01 = __shfl(pk0[1], srcA);
      int a02 = __shfl(pk0[0], srcB), a03 = __shfl(pk0[1], srcB);
      int b00 = __shfl(pk1[0], srcA), b01 = __shfl(pk1[1], srcA);
      int b02 = __shfl(pk1[0], srcB), b03 = __shfl(pk1[1], srcB);
      g1pa0 = mkfrag(cHi ? b00 : a00, cHi ? b01 : a01, cHi ? b02 : a02, cHi ? b03 : a03);
      int a10 = __shfl(pk2[0], srcA), a11 = __shfl(pk2[1], srcA);
      int a12 = __shfl(pk2[0], srcB), a13 = __shfl(pk2[1], srcB);
      int b10 = __shfl(pk3[0], srcA), b11 = __shfl(pk3[1], srcA);
      int b12 = __shfl(pk3[0], srcB), b13 = __shfl(pk3[1], srcB);
      g1pa1 = mkfrag(cHi ? b10 : a10, cHi ? b11 : a11, cHi ? b12 : a12, cHi ? b13 : a13);
    }

    // PV: both groups share vb fragments
    __builtin_amdgcn_s_setprio(1);
#pragma unroll
    for (int nb = 0; nb < 8; ++nb) {
      int vrow = nb * 16 + l15;
      int sw = vrow & 7;
      bf16x8 vb0 = *(const bf16x8*)&Vs[cur][vrow * 64 + ((l4 ^ sw) << 3)];
      o0[nb] = __builtin_amdgcn_mfma_f32_16x16x32_bf16(g0pa0, vb0, o0[nb], 0, 0, 0);
      o1[nb] = __builtin_amdgcn_mfma_f32_16x16x32_bf16(g1pa0, vb0, o1[nb], 0, 0, 0);
      bf16x8 vb1 = *(const bf16x8*)&Vs[cur][vrow * 64 + (((4 + l4) ^ sw) << 3)];
      o0[nb] = __builtin_amdgcn_mfma_f32_16x16x32_bf16(g0pa1, vb1, o0[nb], 0, 0, 0);
      o1[nb] = __builtin_amdgcn_mfma_f32_16x16x32_bf16(g1pa1, vb1, o1[nb], 0, 0, 0);
    }
    __builtin_amdgcn_s_setprio(0);
  }

  // epilogue: y[token][h*128 + d] = o / l
  {
    float lr[4];
#pragma unroll
    for (int r = 0; r < 4; ++r) lr[r] = __shfl(l0s, l4 * 4 + r);
#pragma unroll
    for (int nb = 0; nb < 8; ++nb)
#pragma unroll
      for (int r = 0; r < 4; ++r) {
        int qrow = tb + q0 + l4 * 4 + r;
        y[(size_t)qrow * C_ + h * DH_ + nb * 16 + l15] = f2bf(o0[nb][r] / lr[r]);
      }
  }
  {
    float lr[4];
#pragma unroll
    for (int r = 0; r < 4; ++r) lr[r] = __shfl(l1s, l4 * 4 + r);
#pragma unroll
    for (int nb = 0; nb < 8; ++nb)
#pragma unroll
      for (int r = 0; r < 4; ++r) {
        int qrow = tb + q0 + 16 + l4 * 4 + r;
        y[(size_t)qrow * C_ + h * DH_ + nb * 16 + l15] = f2bf(o1[nb][r] / lr[r]);
      }
  }
}

// ---------------- launch ----------------------------------------------------
extern "C" void kernel_launch(void* const* d_in, const int* in_sizes, int n_in,
                              void* d_out, int out_size, void* d_ws, size_t ws_size,
                              hipStream_t stream) {
  (void)in_sizes; (void)n_in; (void)out_size; (void)ws_size;
  const void* x  = d_in[0];
  const void* Wq = d_in[1];
  const void* Wk = d_in[2];
  const void* Wv = d_in[3];
  const void* Wo = d_in[4];

  char* ws = (char*)d_ws;
  ushort_t* xb  = (ushort_t*)(ws + OFF_XB);   // also reused as y
  ushort_t* WT  = (ushort_t*)(ws + OFF_WT);
  ushort_t* WoT = (ushort_t*)(ws + OFF_WOT);
  ushort_t* qkv = (ushort_t*)(ws + OFF_QKV);
  ushort_t* vTp = (ushort_t*)(ws + OFF_VT);
  int* flag     = (int*)(ws + OFF_FLAG);

  detect_dtype<<<1, 1, 0, stream>>>((const ushort_t*)x, flag);

  // x -> bf16
  cast_x<<<4096, 256, 0, stream>>>(x, xb, flag, (BT_ * C_) / 8);

  // weights -> transposed bf16
  transpose_cast<<<dim3(64, 64), 256, 0, stream>>>(Wq, WT, flag, 2048, 2048, 2048, 0);
  transpose_cast<<<dim3(4, 64), 256, 0, stream>>>(Wk, WT, flag, 2048, 128, 2048, 2048);
  transpose_cast<<<dim3(4, 64), 256, 0, stream>>>(Wv, WT, flag, 2048, 128, 2048, 2176);
  transpose_cast<<<dim3(64, 64), 256, 0, stream>>>(Wo, WoT, flag, 2048, 2048, 2048, 0);

  // qkv = xb @ WT^T ; q columns pre-scaled by 1/sqrt(128)*log2(e) for exp2 softmax
  const float k1 = 0.08838834764831845f * 1.4426950408889634f;
  gemm_bt<<<dim3(NQKV / 128, BT_ / 128), 256, 0, stream>>>(xb, WT, qkv, BT_, NQKV, C_, 0, flag, k1, 2048);

  // v -> vT
  transpose_v<<<dim3(T_ / 32, DH_ / 32, B_), 256, 0, stream>>>(qkv, vTp);

  // attention -> y (reuses xb buffer); 1 head/block, 512 blocks = 2/CU
  attn_kernel<<<dim3(T_ / 128, H_, B_), 256, 0, stream>>>(qkv, vTp, xb);

  // out = y @ WoT^T
  gemm_bt<<<dim3(C_ / 128, BT_ / 128), 256, 0, stream>>>(xb, WoT, d_out, BT_, C_, C_, 1, flag, 1.0f, 0);
}

// Round 8
// 320.548 us; speedup vs baseline: 1.6665x; 1.0755x over previous
//
#include <hip/hip_runtime.h>

typedef unsigned short ushort_t;
typedef short bf16x8 __attribute__((ext_vector_type(8)));
typedef float f32x4 __attribute__((ext_vector_type(4)));
typedef float f32x16 __attribute__((ext_vector_type(16)));

#define B_    2
#define T_    2048
#define C_    2048
#define H_    16
#define DH_   128
#define BT_   4096
#define NQKV  2304

// workspace offsets (bytes), all 256-aligned
#define OFF_XB   0UL            // xb (bf16 x) [4096][2048] ; reused as y after attention
#define OFF_WT   16777216UL     // WT_all [2304][2048] bf16
#define OFF_WOT  26214400UL     // WoT [2048][2048] bf16
#define OFF_QKV  34603008UL     // qkv [4096][2304] bf16 (q cols pre-scaled by 1/sqrt(128)*log2e)
#define OFF_VT   53477376UL     // vT [2][128][2048] bf16
#define OFF_FLAG 54525952UL     // int flag: 1 = inputs are bf16, 0 = fp32

__device__ __forceinline__ ushort_t f2bf(float f) {
  union { float f; unsigned u; } v; v.f = f;
  unsigned r = v.u + 0x7fffu + ((v.u >> 16) & 1u);
  return (ushort_t)(r >> 16);
}
__device__ __forceinline__ float bf2f(ushort_t u) {
  union { float f; unsigned u; } v; v.u = ((unsigned)u) << 16;
  return v.f;
}
__device__ __forceinline__ int cvtpk_bf16(float lo, float hi) {
  int r;
  asm("v_cvt_pk_bf16_f32 %0, %1, %2" : "=v"(r) : "v"(lo), "v"(hi));
  return r;
}
// v_permlane32_swap_b32: x' = {x.lo, y.lo}, y' = {x.hi, y.hi}
__device__ __forceinline__ void plswap(int& x, int& y) {
  asm volatile("v_permlane32_swap_b32 %0, %1" : "+v"(x), "+v"(y));
}
__device__ __forceinline__ bf16x8 mkfrag(int d0, int d1, int d2, int d3) {
  union { int i[4]; bf16x8 v; } u;
  u.i[0] = d0; u.i[1] = d1; u.i[2] = d2; u.i[3] = d3;
  return u.v;
}

__device__ __forceinline__ void gload_lds16(const ushort_t* g, ushort_t* l) {
  __builtin_amdgcn_global_load_lds((__attribute__((address_space(1))) void*)g,
                                   (__attribute__((address_space(3))) void*)l,
                                   16, 0, 0);
}

// ---------------- dtype detector -------------------------------------------
__global__ void detect_dtype(const ushort_t* x, int* flag) {
  if (threadIdx.x == 0 && blockIdx.x == 0) {
    int sane = 0;
    for (int i = 0; i < 32; ++i) {
      ushort_t u = x[2 * i];
      int e = (u >> 7) & 0xFF;
      if (u == 0 || (e >= 100 && e <= 140)) ++sane;
    }
    *flag = (sane >= 24) ? 1 : 0;
  }
}

// ---------------- cast x -> bf16 -------------------------------------------
__global__ __launch_bounds__(256) void cast_x(const void* __restrict__ xin,
                                              ushort_t* __restrict__ xb,
                                              const int* __restrict__ flag, int n8) {
  int i = blockIdx.x * 256 + threadIdx.x;
  if (i >= n8) return;
  if (*flag) {
    *(bf16x8*)(xb + (size_t)i * 8) = *(const bf16x8*)((const ushort_t*)xin + (size_t)i * 8);
  } else {
    const float* xf = (const float*)xin;
    f32x4 a = *(const f32x4*)(xf + (size_t)i * 8);
    f32x4 b = *(const f32x4*)(xf + (size_t)i * 8 + 4);
    bf16x8 o;
    o[0] = (short)f2bf(a[0]); o[1] = (short)f2bf(a[1]);
    o[2] = (short)f2bf(a[2]); o[3] = (short)f2bf(a[3]);
    o[4] = (short)f2bf(b[0]); o[5] = (short)f2bf(b[1]);
    o[6] = (short)f2bf(b[2]); o[7] = (short)f2bf(b[3]);
    *(bf16x8*)(xb + (size_t)i * 8) = o;
  }
}

// ---------------- transpose+cast weight: dst[row_off+c][r] = src[r][c] -----
__global__ __launch_bounds__(256) void transpose_cast(const void* __restrict__ src,
                                                      ushort_t* __restrict__ dst,
                                                      const int* __restrict__ flag,
                                                      int rows, int cols, int dst_ld,
                                                      int dst_row_off) {
  __shared__ float tile[32][33];
  int c0 = blockIdx.x * 32, r0 = blockIdx.y * 32;
  int tx = threadIdx.x & 31, ty = threadIdx.x >> 5;  // 32 x 8
  bool isbf = (*flag != 0);
#pragma unroll
  for (int j = 0; j < 4; ++j) {
    int r = r0 + ty + j * 8;
    float v;
    if (isbf) v = bf2f(((const ushort_t*)src)[(size_t)r * cols + c0 + tx]);
    else      v = ((const float*)src)[(size_t)r * cols + c0 + tx];
    tile[ty + j * 8][tx] = v;
  }
  __syncthreads();
#pragma unroll
  for (int j = 0; j < 4; ++j) {
    int c = c0 + ty + j * 8;
    dst[(size_t)(dst_row_off + c) * dst_ld + r0 + tx] = f2bf(tile[tx][ty + j * 8]);
  }
}

// ---------------- transpose v slice of qkv -> vT (bf16) --------------------
__global__ __launch_bounds__(256) void transpose_v(const ushort_t* __restrict__ qkv,
                                                   ushort_t* __restrict__ vT) {
  __shared__ ushort_t tile[32][33];
  int b = blockIdx.z;
  int t0 = blockIdx.x * 32, d0 = blockIdx.y * 32;
  int tx = threadIdx.x & 31, ty = threadIdx.x >> 5;
#pragma unroll
  for (int j = 0; j < 4; ++j) {
    int t = t0 + ty + j * 8;
    tile[ty + j * 8][tx] = qkv[(size_t)(b * T_ + t) * NQKV + 2176 + d0 + tx];
  }
  __syncthreads();
#pragma unroll
  for (int j = 0; j < 4; ++j) {
    int d = d0 + ty + j * 8;
    vT[(size_t)b * (DH_ * T_) + (size_t)d * T_ + t0 + tx] = tile[tx][ty + j * 8];
  }
}

// ---------------- GEMM: C[m][n] = sum_k A[m][k] * Bt[n][k]  (bf16 MFMA) ----
// 128x128 tile, BK=32, 256 threads = 4 waves (2x2), each wave 64x64.
// Double-buffered LDS + counted vmcnt(4) + raw barriers; bijective XCD swizzle.
__global__ __launch_bounds__(256) void gemm_bt(const ushort_t* __restrict__ A,
                                               const ushort_t* __restrict__ Bt,
                                               void* __restrict__ Cv,
                                               int M, int N, int K,
                                               int is_final, const int* __restrict__ flag,
                                               float qscale, int qcols) {
  __shared__ __align__(16) ushort_t As[2][128 * 32];
  __shared__ __align__(16) ushort_t Bs[2][128 * 32];
  const int tid = threadIdx.x;
  const int lane = tid & 63;
  const int wid = tid >> 6;

  // bijective XCD swizzle (m204): contiguous grid chunk per XCD
  const int gx = gridDim.x;
  const int nwg = gx * gridDim.y;
  const int orig = blockIdx.y * gx + blockIdx.x;
  const int qq = nwg >> 3, rr = nwg & 7;
  const int xcd = orig & 7, pos = orig >> 3;
  const int wg = (xcd < rr ? xcd * (qq + 1) : rr * (qq + 1) + (xcd - rr) * qq) + pos;
  const int bx = wg % gx, by = wg / gx;

  const int m0 = by * 128;
  const int n0 = bx * 128;
  const int wr = wid >> 1, wc = wid & 1;
  const int l15 = lane & 15, l4 = lane >> 4;

  f32x4 zero = {0.f, 0.f, 0.f, 0.f};
  f32x4 acc[4][4];
#pragma unroll
  for (int r = 0; r < 4; ++r)
#pragma unroll
    for (int c = 0; c < 4; ++c) acc[r][c] = zero;

  const ushort_t* ga = A + (size_t)(m0 + (tid >> 2)) * K + (tid & 3) * 8;
  const ushort_t* gb = Bt + (size_t)(n0 + (tid >> 2)) * K + (tid & 3) * 8;
  const size_t stride64 = (size_t)64 * K;
  const int lofs = wid * 512;  // wave-uniform LDS base (elements)

  // prologue: stage tile 0 into buffer 0
  gload_lds16(ga, As[0] + lofs);
  gload_lds16(ga + stride64, As[0] + lofs + 2048);
  gload_lds16(gb, Bs[0] + lofs);
  gload_lds16(gb + stride64, Bs[0] + lofs + 2048);

  const int NT = K >> 5;
  for (int t = 0; t < NT; ++t) {
    const int cur = t & 1;
    if (t + 1 < NT) {
      const int k1 = (t + 1) << 5;
      gload_lds16(ga + k1, As[cur ^ 1] + lofs);
      gload_lds16(ga + k1 + stride64, As[cur ^ 1] + lofs + 2048);
      gload_lds16(gb + k1, Bs[cur ^ 1] + lofs);
      gload_lds16(gb + k1 + stride64, Bs[cur ^ 1] + lofs + 2048);
      asm volatile("s_waitcnt vmcnt(4)" ::: "memory");  // tile t landed; t+1 in flight
    } else {
      asm volatile("s_waitcnt vmcnt(0)" ::: "memory");
    }
    __builtin_amdgcn_s_barrier();  // whole tile t visible to all waves

    bf16x8 af[4], bfr[4];
#pragma unroll
    for (int r = 0; r < 4; ++r)
      af[r] = *(const bf16x8*)&As[cur][(wr * 64 + r * 16 + l15) * 32 + l4 * 8];
#pragma unroll
    for (int c = 0; c < 4; ++c)
      bfr[c] = *(const bf16x8*)&Bs[cur][(wc * 64 + c * 16 + l15) * 32 + l4 * 8];
    __builtin_amdgcn_s_setprio(1);
#pragma unroll
    for (int r = 0; r < 4; ++r)
#pragma unroll
      for (int c = 0; c < 4; ++c)
        acc[r][c] = __builtin_amdgcn_mfma_f32_16x16x32_bf16(af[r], bfr[c], acc[r][c], 0, 0, 0);
    __builtin_amdgcn_s_setprio(0);
    __builtin_amdgcn_s_barrier();  // all waves done reading buf[cur]
  }

  const bool f32out = is_final && (*flag == 0);
#pragma unroll
  for (int r = 0; r < 4; ++r) {
#pragma unroll
    for (int c = 0; c < 4; ++c) {
      int row = m0 + wr * 64 + r * 16 + l4 * 4;
      int col = n0 + wc * 64 + c * 16 + l15;
      float s = (col < qcols) ? qscale : 1.0f;
#pragma unroll
      for (int g = 0; g < 4; ++g) {
        float v = acc[r][c][g] * s;
        if (f32out) ((float*)Cv)[(size_t)(row + g) * N + col] = v;
        else ((ushort_t*)Cv)[(size_t)(row + g) * N + col] = f2bf(v);
      }
    }
  }
}

// ---------------- flash attention (v6: 32x32 MFMA) ---------------------------
// grid (16 qtiles, 16 heads, 2 batches) = 512 blocks, 256 threads = 4 waves.
// Each wave: ONE 32-q group via mfma_f32_32x32x16_bf16 (C/D: col=lane&31,
// row=(reg&3)+8*(reg>>2)+4*(lane>>5)). Swapped QK^T (A=K,B=Q) -> lane owns
// q=lane&31 with 16 s-values; pair lane^32 holds the other 16 -> softmax is
// 31 fmax + ONE shfl_xor(32). P C-frag -> PV A-frag via 16 cvt_pk + 8
// v_permlane32_swap_b32 (replaces 72 ds_bpermute). Staging identical to v5b.
__global__ __launch_bounds__(256, 2) void attn_kernel(const ushort_t* __restrict__ qkv,
                                                      const ushort_t* __restrict__ vT,
                                                      ushort_t* __restrict__ y) {
  __shared__ __align__(16) ushort_t Ks[2][64 * 128];
  __shared__ __align__(16) ushort_t Vs[2][128 * 64];

  const int tid = threadIdx.x;
  const int lane = tid & 63;
  const int wid = tid >> 6;                 // 0..3
  const int h = blockIdx.y;
  const int b = blockIdx.z;
  const int tb = b * T_;
  const int q0 = blockIdx.x * 128 + wid * 32;
  const int l31 = lane & 31, hi = lane >> 5;

  // Q B-frags: qf[kk] = Q[q0+l31][kk*16 + hi*8 .. +8]  (pre-scaled)
  bf16x8 qf[8];
  {
    const ushort_t* qb = qkv + (size_t)(tb + q0 + l31) * NQKV + h * DH_ + hi * 8;
#pragma unroll
    for (int kk = 0; kk < 8; ++kk) qf[kk] = *(const bf16x8*)(qb + kk * 16);
  }

  // staging addresses (pre-swizzled global source, linear LDS dest)
  // K tile and V tile: 1024 16B-chunks each -> 4 per thread at 256 threads.
  const ushort_t* ksrcb[4];
  const ushort_t* vsrcb[4];
  int koff[4], voff[4];
#pragma unroll
  for (int it = 0; it < 4; ++it) {
    int id = tid + it * 256;
    int krow = id >> 4, kslot = id & 15;
    ksrcb[it] = qkv + (size_t)(tb + krow) * NQKV + 2048 + ((kslot ^ (krow & 7)) << 3);
    koff[it] = (it * 256 + (wid << 6)) * 8;  // wave-uniform within buffer
    int vrow = id >> 3, vslot = id & 7;
    vsrcb[it] = vT + (size_t)b * (DH_ * T_) + (size_t)vrow * T_ + ((vslot ^ (vrow & 7)) << 3);
    voff[it] = (it * 256 + (wid << 6)) * 8;
  }

  f32x16 o[4];
#pragma unroll
  for (int d = 0; d < 4; ++d)
#pragma unroll
    for (int r = 0; r < 16; ++r) o[d][r] = 0.f;
  float m_s = -1e30f;
  float l_s = 0.f;

  // prologue: stage tile 0 into buffer 0
#pragma unroll
  for (int it = 0; it < 4; ++it) {
    gload_lds16(ksrcb[it], &Ks[0][koff[it]]);
    gload_lds16(vsrcb[it], &Vs[0][voff[it]]);
  }

  for (int st = 0; st < 32; ++st) {
    const int cur = st & 1;
    __syncthreads();  // drains tile-st loads; buf[cur^1] free for prefetch
    if (st < 31) {
      const int s1 = (st + 1) * 64;
#pragma unroll
      for (int it = 0; it < 4; ++it) {
        gload_lds16(ksrcb[it] + (size_t)s1 * NQKV, &Ks[cur ^ 1][koff[it]]);
        gload_lds16(vsrcb[it] + s1, &Vs[cur ^ 1][voff[it]]);
      }
    }

    // S^T = K Q^T : sa0 = s 0..31, sa1 = s 32..63; lane: q = l31, 16 s each
    f32x16 sa0, sa1;
#pragma unroll
    for (int r = 0; r < 16; ++r) { sa0[r] = 0.f; sa1[r] = 0.f; }
    const int r0 = l31, r1 = 32 + l31;
    const int sw0 = r0 & 7, sw1 = r1 & 7;
    __builtin_amdgcn_s_setprio(1);
#pragma unroll
    for (int kk = 0; kk < 8; ++kk) {
      bf16x8 k0 = *(const bf16x8*)&Ks[cur][r0 * 128 + (((kk * 2 + hi) ^ sw0) << 3)];
      bf16x8 k1 = *(const bf16x8*)&Ks[cur][r1 * 128 + (((kk * 2 + hi) ^ sw1) << 3)];
      sa0 = __builtin_amdgcn_mfma_f32_32x32x16_bf16(k0, qf[kk], sa0, 0, 0, 0);
      sa1 = __builtin_amdgcn_mfma_f32_32x32x16_bf16(k1, qf[kk], sa1, 0, 0, 0);
    }
    __builtin_amdgcn_s_setprio(0);

    // lane-local online softmax over 32 values; pair lane^32 has the rest
    float pmax = sa0[0];
#pragma unroll
    for (int r = 1; r < 16; ++r) pmax = fmaxf(pmax, sa0[r]);
#pragma unroll
    for (int r = 0; r < 16; ++r) pmax = fmaxf(pmax, sa1[r]);
    pmax = fmaxf(pmax, __shfl_xor(pmax, 32));

    if (!__all(pmax - m_s <= 8.0f)) {  // defer-max
      float mn = fmaxf(m_s, pmax);
      float al = exp2f(m_s - mn);
      m_s = mn; l_s *= al;
      float ar[16];
#pragma unroll
      for (int r = 0; r < 16; ++r) ar[r] = __shfl(al, (r & 3) + 8 * (r >> 2) + 4 * hi);
#pragma unroll
      for (int d = 0; d < 4; ++d)
#pragma unroll
        for (int r = 0; r < 16; ++r) o[d][r] *= ar[r];
    }

    float ps = 0.f;
#pragma unroll
    for (int r = 0; r < 16; ++r) {
      float p = exp2f(sa0[r] - m_s);
      sa0[r] = p; ps += p;
    }
#pragma unroll
    for (int r = 0; r < 16; ++r) {
      float p = exp2f(sa1[r] - m_s);
      sa1[r] = p; ps += p;
    }
    ps += __shfl_xor(ps, 32);
    l_s += ps;

    // P -> A-frags: per s-half, 8 cvt_pk + 4 permlane32_swap -> 2 frags
    bf16x8 pa0, pa1, pa2, pa3;
    {
      int a = cvtpk_bf16(sa0[0], sa0[1]),  b2 = cvtpk_bf16(sa0[2], sa0[3]);
      int c = cvtpk_bf16(sa0[4], sa0[5]),  d2 = cvtpk_bf16(sa0[6], sa0[7]);
      int e = cvtpk_bf16(sa0[8], sa0[9]),  f2 = cvtpk_bf16(sa0[10], sa0[11]);
      int g = cvtpk_bf16(sa0[12], sa0[13]), h2 = cvtpk_bf16(sa0[14], sa0[15]);
      plswap(a, c);  plswap(b2, d2);   // a,b2 = dw0,dw1 ; c,d2 = dw2,dw3
      plswap(e, g);  plswap(f2, h2);
      pa0 = mkfrag(a, b2, c, d2);
      pa1 = mkfrag(e, f2, g, h2);
    }
    {
      int a = cvtpk_bf16(sa1[0], sa1[1]),  b2 = cvtpk_bf16(sa1[2], sa1[3]);
      int c = cvtpk_bf16(sa1[4], sa1[5]),  d2 = cvtpk_bf16(sa1[6], sa1[7]);
      int e = cvtpk_bf16(sa1[8], sa1[9]),  f2 = cvtpk_bf16(sa1[10], sa1[11]);
      int g = cvtpk_bf16(sa1[12], sa1[13]), h2 = cvtpk_bf16(sa1[14], sa1[15]);
      plswap(a, c);  plswap(b2, d2);
      plswap(e, g);  plswap(f2, h2);
      pa2 = mkfrag(a, b2, c, d2);
      pa3 = mkfrag(e, f2, g, h2);
    }

    // PV: o[q][d] += P[q][s] V[s][d] ; B-frag from Vs (V^T), s-chunks of 16
    __builtin_amdgcn_s_setprio(1);
#pragma unroll
    for (int dblk = 0; dblk < 4; ++dblk) {
      int vrow = dblk * 32 + l31;
      int vsw = vrow & 7;
      bf16x8 v0 = *(const bf16x8*)&Vs[cur][vrow * 64 + (((0 * 2 + hi) ^ vsw) << 3)];
      o[dblk] = __builtin_amdgcn_mfma_f32_32x32x16_bf16(pa0, v0, o[dblk], 0, 0, 0);
      bf16x8 v1 = *(const bf16x8*)&Vs[cur][vrow * 64 + (((1 * 2 + hi) ^ vsw) << 3)];
      o[dblk] = __builtin_amdgcn_mfma_f32_32x32x16_bf16(pa1, v1, o[dblk], 0, 0, 0);
      bf16x8 v2 = *(const bf16x8*)&Vs[cur][vrow * 64 + (((2 * 2 + hi) ^ vsw) << 3)];
      o[dblk] = __builtin_amdgcn_mfma_f32_32x32x16_bf16(pa2, v2, o[dblk], 0, 0, 0);
      bf16x8 v3 = *(const bf16x8*)&Vs[cur][vrow * 64 + (((3 * 2 + hi) ^ vsw) << 3)];
      o[dblk] = __builtin_amdgcn_mfma_f32_32x32x16_bf16(pa3, v3, o[dblk], 0, 0, 0);
    }
    __builtin_amdgcn_s_setprio(0);
  }

  // epilogue: y[q][h*128+d] = o / l ; o reg r -> q = (r&3)+8*(r>>2)+4*hi
  float inv_l = 1.0f / l_s;
  float rl[16];
#pragma unroll
  for (int r = 0; r < 16; ++r) rl[r] = __shfl(inv_l, (r & 3) + 8 * (r >> 2) + 4 * hi);
#pragma unroll
  for (int dblk = 0; dblk < 4; ++dblk) {
#pragma unroll
    for (int r = 0; r < 16; ++r) {
      int qr = (r & 3) + 8 * (r >> 2) + 4 * hi;
      y[(size_t)(tb + q0 + qr) * C_ + h * DH_ + dblk * 32 + l31] = f2bf(o[dblk][r] * rl[r]);
    }
  }
}

// ---------------- launch ----------------------------------------------------
extern "C" void kernel_launch(void* const* d_in, const int* in_sizes, int n_in,
                              void* d_out, int out_size, void* d_ws, size_t ws_size,
                              hipStream_t stream) {
  (void)in_sizes; (void)n_in; (void)out_size; (void)ws_size;
  const void* x  = d_in[0];
  const void* Wq = d_in[1];
  const void* Wk = d_in[2];
  const void* Wv = d_in[3];
  const void* Wo = d_in[4];

  char* ws = (char*)d_ws;
  ushort_t* xb  = (ushort_t*)(ws + OFF_XB);   // also reused as y
  ushort_t* WT  = (ushort_t*)(ws + OFF_WT);
  ushort_t* WoT = (ushort_t*)(ws + OFF_WOT);
  ushort_t* qkv = (ushort_t*)(ws + OFF_QKV);
  ushort_t* vTp = (ushort_t*)(ws + OFF_VT);
  int* flag     = (int*)(ws + OFF_FLAG);

  detect_dtype<<<1, 1, 0, stream>>>((const ushort_t*)x, flag);

  // x -> bf16
  cast_x<<<4096, 256, 0, stream>>>(x, xb, flag, (BT_ * C_) / 8);

  // weights -> transposed bf16
  transpose_cast<<<dim3(64, 64), 256, 0, stream>>>(Wq, WT, flag, 2048, 2048, 2048, 0);
  transpose_cast<<<dim3(4, 64), 256, 0, stream>>>(Wk, WT, flag, 2048, 128, 2048, 2048);
  transpose_cast<<<dim3(4, 64), 256, 0, stream>>>(Wv, WT, flag, 2048, 128, 2048, 2176);
  transpose_cast<<<dim3(64, 64), 256, 0, stream>>>(Wo, WoT, flag, 2048, 2048, 2048, 0);

  // qkv = xb @ WT^T ; q columns pre-scaled by 1/sqrt(128)*log2(e) for exp2 softmax
  const float k1 = 0.08838834764831845f * 1.4426950408889634f;
  gemm_bt<<<dim3(NQKV / 128, BT_ / 128), 256, 0, stream>>>(xb, WT, qkv, BT_, NQKV, C_, 0, flag, k1, 2048);

  // v -> vT
  transpose_v<<<dim3(T_ / 32, DH_ / 32, B_), 256, 0, stream>>>(qkv, vTp);

  // attention -> y (reuses xb buffer); 1 head/block, 512 blocks
  attn_kernel<<<dim3(T_ / 128, H_, B_), 256, 0, stream>>>(qkv, vTp, xb);

  // out = y @ WoT^T
  gemm_bt<<<dim3(C_ / 128, BT_ / 128), 256, 0, stream>>>(xb, WoT, d_out, BT_, C_, C_, 1, flag, 1.0f, 0);
}